// Round 9
// baseline (355.921 us; speedup 1.0000x reference)
//
#include <hip/hip_runtime.h>
#include <math.h>

typedef unsigned short u16;

#define NN 2
#define CC 128
#define HH 64
#define WW 64
#define NHD 4
#define DH 32
#define KSZ 7
#define PIX (NN*HH*WW)          // 8192
#define HID 512
#define C4 32
#define CRED 7
#define RW 22
#define RNB 160
#define NBV 154

typedef float f32x4 __attribute__((ext_vector_type(4)));
typedef short bf16x8 __attribute__((ext_vector_type(8)));

static __device__ __forceinline__ float u2f(u16 u){ return __uint_as_float(((unsigned)u) << 16); }
static __device__ __forceinline__ u16 f2u(float f){
    unsigned b = __float_as_uint(f);
    return (u16)((b + 0x7FFFu + ((b >> 16) & 1u)) >> 16);
}

// ---------------- dtype sniffer + zero accumulators ----------------
__global__ void detect_k(const u16* __restrict__ x, int* __restrict__ flag,
                         float* __restrict__ poolacc){
    __shared__ float red[256];
    int t = threadIdx.x;
    float mx = 0.f;
    for(int i = t; i < 4096; i += 256){
        float v = fabsf(u2f(x[i]));
        if(v < 1e30f) mx = fmaxf(mx, v);
    }
    red[t] = mx; __syncthreads();
    for(int s = 128; s > 0; s >>= 1){
        if(t < s) red[t] = fmaxf(red[t], red[t+s]);
        __syncthreads();
    }
    if(t == 0) *flag = (red[0] > 1e6f) ? 1 : 0;
    if(t < NN*CC) poolacc[t] = 0.f;
}

// ---------------- combined setup: weight cvt + conv repack + NCHW + GN partials ----------------
struct PtrTab { const void* p[23]; int off[24]; };
#define NCVT 2172
#define NRPK 576
#define NNCH 512

__global__ __launch_bounds__(256) void setup_k(
    PtrTab tab, u16* __restrict__ Wb, u16* __restrict__ Wt,
    const void* __restrict__ convw, const void* __restrict__ x,
    float* __restrict__ cur, float* __restrict__ part,
    const int* __restrict__ flag, int total)
{
    int blk = blockIdx.x;
    int t = threadIdx.x;
    int fl = *flag;
    if(blk < NCVT){
        int i = blk*256 + t;
        if(i < total){
            int a = 0;
            while(i >= tab.off[a+1]) a++;
            int loc = i - tab.off[a];
            Wb[i] = fl ? f2u(((const float*)tab.p[a])[loc]) : ((const u16*)tab.p[a])[loc];
        }
        return;
    }
    if(blk < NCVT + NRPK){
        int i = (blk - NCVT)*256 + t;
        if(i < CC*CC*9){
            int o = i/(9*CC); int rem = i%(9*CC); int tap = rem/CC; int c = rem%CC;
            size_t s = (size_t)(o*CC + c)*9 + tap;
            Wt[i] = fl ? f2u(((const float*)convw)[s]) : ((const u16*)convw)[s];
        }
        return;
    }
    __shared__ float tile[32][65];
    __shared__ float wred[4][2];
    int u = blk - NCVT - NRPK;
    int bx = u & 3, by = u >> 2;
    int n = by >> 6, i = by & 63;
    for(int idx = t; idx < 32*64; idx += 256){
        int cl = idx >> 6, j = idx & 63;
        size_t src = ((size_t)(n*CC + bx*32 + cl)*HH + i)*WW + j;
        tile[cl][j] = fl ? ((const float*)x)[src] : u2f(((const u16*)x)[src]);
    }
    __syncthreads();
    float s = 0.f, q = 0.f;
    for(int idx = t; idx < 64*32; idx += 256){
        int j = idx >> 5, cl = idx & 31;
        float v = tile[cl][j];
        cur[((size_t)((n*HH + i)*WW) + j)*CC + bx*32 + cl] = v;
        s += v; q += v*v;
    }
    #pragma unroll
    for(int off = 32; off > 0; off >>= 1){ s += __shfl_xor(s, off, 64); q += __shfl_xor(q, off, 64); }
    int wave = t >> 6;
    if((t & 63) == 0){ wred[wave][0] = s; wred[wave][1] = q; }
    __syncthreads();
    if(t == 0){
        float ss = wred[0][0]+wred[1][0]+wred[2][0]+wred[3][0];
        float qq = wred[0][1]+wred[1][1]+wred[2][1]+wred[3][1];
        int pidx = n*256 + i*4 + bx;
        part[pidx*2] = ss; part[pidx*2+1] = qq;
    }
}

// ---------------- MFMA GEMM, 64x64 tile, BK=128 (qkv with fused GN-on-A) ----------------
enum { EPI_NONE = 0, EPI_RES = 1, EPI_GELU = 2 };
enum { OUT_F32 = 0, OUT_BF16 = 1, OUT_BOTH = 2 };
enum { EX_NONE = 0, EX_STATS = 1 };
#define LDP 136

template<int EPI, int OUTM, int AGN, int EXTRA>
__global__ __launch_bounds__(256) void g64_k(
    const void* __restrict__ Av, const u16* __restrict__ W, const u16* __restrict__ bias,
    const float* __restrict__ R, float* __restrict__ Cf, u16* __restrict__ Cb,
    const u16* __restrict__ gnw, const u16* __restrict__ gnb,
    float* __restrict__ gnpart, int gncount,
    int M, int N, int K)
{
    __shared__ __align__(16) u16 As[64*LDP];
    __shared__ __align__(16) u16 Bs[64*LDP];
    __shared__ float wred[4][2];
    const int bm = blockIdx.y*64, bn = blockIdx.x*64;
    const int t = threadIdx.x;
    const int wave = t >> 6, lane = t & 63;
    const int wm = (wave >> 1)*32, wn = (wave & 1)*32;
    const int lg = lane >> 4, lr = lane & 15;
    const int nsm = bm >> 12;
    f32x4 acc[2][2];
    #pragma unroll
    for(int i = 0; i < 2; i++)
        #pragma unroll
        for(int j = 0; j < 2; j++) acc[i][j] = (f32x4){0.f,0.f,0.f,0.f};

    float gmu = 0.f, grs = 0.f;
    if(AGN){
        float a = 0.f, q = 0.f;
        for(int idx = lane; idx < gncount; idx += 64){
            a += gnpart[(nsm*gncount + idx)*2];
            q += gnpart[(nsm*gncount + idx)*2 + 1];
        }
        #pragma unroll
        for(int off = 32; off > 0; off >>= 1){
            a += __shfl_xor(a, off, 64); q += __shfl_xor(q, off, 64);
        }
        const float inv = 1.f/(float)(HH*WW*CC);
        gmu = a*inv;
        grs = rsqrtf(fmaxf(q*inv - gmu*gmu, 0.f) + 1e-5f);
    }

    for(int k0 = 0; k0 < K; k0 += 128){
        uint4 ra[4], rb[4];
        float4 fa[4][2];
        #pragma unroll
        for(int r = 0; r < 4; r++){
            int e = r*256 + t;
            int row = e >> 4, ch = e & 15;
            if(AGN){
                const float* ap = (const float*)Av + (size_t)(bm+row)*K + k0 + ch*8;
                fa[r][0] = *(const float4*)ap;
                fa[r][1] = *(const float4*)(ap + 4);
            } else {
                ra[r] = *(const uint4*)((const u16*)Av + (size_t)(bm+row)*K + k0 + ch*8);
            }
            rb[r] = (bn+row < N) ? *(const uint4*)(W + (size_t)(bn+row)*K + k0 + ch*8)
                                 : (uint4){0,0,0,0};
        }
        #pragma unroll
        for(int r = 0; r < 4; r++){
            int e = r*256 + t;
            int row = e >> 4, ch = e & 15;
            if(AGN){
                union { uint4 u; u16 h[8]; } g8, b8, o8;
                g8.u = *(const uint4*)(gnw + k0 + ch*8);
                b8.u = *(const uint4*)(gnb + k0 + ch*8);
                const float* fv = (const float*)&fa[r][0];
                #pragma unroll
                for(int z = 0; z < 8; z++)
                    o8.h[z] = f2u((fv[z]-gmu)*grs*u2f(g8.h[z]) + u2f(b8.h[z]));
                *(uint4*)&As[row*LDP + ch*8] = o8.u;
            } else {
                *(uint4*)&As[row*LDP + ch*8] = ra[r];
            }
            *(uint4*)&Bs[row*LDP + ch*8] = rb[r];
        }
        __syncthreads();
        #pragma unroll
        for(int kc = 0; kc < 4; kc++){
            bf16x8 af0 = *(const bf16x8*)&As[(wm + lr)*LDP      + kc*32 + lg*8];
            bf16x8 af1 = *(const bf16x8*)&As[(wm + 16 + lr)*LDP + kc*32 + lg*8];
            bf16x8 bf0 = *(const bf16x8*)&Bs[(wn + lr)*LDP      + kc*32 + lg*8];
            bf16x8 bf1 = *(const bf16x8*)&Bs[(wn + 16 + lr)*LDP + kc*32 + lg*8];
            acc[0][0] = __builtin_amdgcn_mfma_f32_16x16x32_bf16(af0, bf0, acc[0][0], 0, 0, 0);
            acc[0][1] = __builtin_amdgcn_mfma_f32_16x16x32_bf16(af0, bf1, acc[0][1], 0, 0, 0);
            acc[1][0] = __builtin_amdgcn_mfma_f32_16x16x32_bf16(af1, bf0, acc[1][0], 0, 0, 0);
            acc[1][1] = __builtin_amdgcn_mfma_f32_16x16x32_bf16(af1, bf1, acc[1][1], 0, 0, 0);
        }
        if(k0 + 128 < K) __syncthreads();
    }

    float ssum = 0.f, sq = 0.f;
    #pragma unroll
    for(int i = 0; i < 2; i++){
        #pragma unroll
        for(int j = 0; j < 2; j++){
            int col = bn + wn + j*16 + lr;
            if(col >= N) continue;
            #pragma unroll
            for(int reg = 0; reg < 4; reg++){
                int row = bm + wm + i*16 + lg*4 + reg;
                float v = acc[i][j][reg] + u2f(bias[col]);
                if(EPI == EPI_RES)  v += R[(size_t)row*N + col];
                if(EPI == EPI_GELU) v = 0.5f*v*(1.f + erff(v*0.70710678118f));
                if(OUTM == OUT_F32 || OUTM == OUT_BOTH) Cf[(size_t)row*N + col] = v;
                if(OUTM == OUT_BF16 || OUTM == OUT_BOTH) Cb[(size_t)row*N + col] = f2u(v);
                if(EXTRA == EX_STATS){ ssum += v; sq += v*v; }
            }
        }
    }
    if(EXTRA == EX_STATS){
        #pragma unroll
        for(int off = 32; off > 0; off >>= 1){
            ssum += __shfl_xor(ssum, off, 64); sq += __shfl_xor(sq, off, 64);
        }
        if(lane == 0){ wred[wave][0] = ssum; wred[wave][1] = sq; }
        __syncthreads();
        if(t == 0){
            int bidx = blockIdx.y*gridDim.x + blockIdx.x;
            gnpart[bidx*2]   = wred[0][0]+wred[1][0]+wred[2][0]+wred[3][0];
            gnpart[bidx*2+1] = wred[0][1]+wred[1][1]+wred[2][1]+wred[3][1];
        }
    }
}

// ---------------- mega-fused MLP: proj+res+LN+fc1+GELU+fc2+res (+GN stats) ----------------
// M-tile 16, full N=128 row per block; 512 blocks; weights streamed through Bs.
#define HSP 520   // Hs row stride (u16)

__global__ __launch_bounds__(256) void mlp_k(
    const u16* __restrict__ A,              // attn-out bf16 [PIX][128]
    const float* __restrict__ curin,        // residual stream f32 (read)
    const u16* __restrict__ projw, const u16* __restrict__ projb,
    const u16* __restrict__ lng, const u16* __restrict__ lnb,
    const u16* __restrict__ f1w, const u16* __restrict__ f1b,
    const u16* __restrict__ f2w, const u16* __restrict__ f2b,
    float* __restrict__ curout, u16* __restrict__ cur16,
    float* __restrict__ gnpart)
{
    __shared__ __align__(16) u16 As[16*LDP];     // attn-out tile
    __shared__ __align__(16) u16 Ls[16*LDP];     // LN-out tile
    __shared__ __align__(16) u16 Bs[128*LDP];    // streamed weights
    __shared__ __align__(16) u16 Hs[16*HSP];     // fc1 hidden (bf16)
    __shared__ float redS[16][4], redQ[16][4], muS[16], rsS[16];
    __shared__ float wred[4][2];
    const int bm = blockIdx.x*16;
    const int t = threadIdx.x;
    const int wave = t >> 6, lane = t & 63;
    const int wn = wave*32;                      // each wave: 16 rows x 32 cols (2 tiles)
    const int lg = lane >> 4, lr = lane & 15;
    const int nsm = bm >> 12;

    // ---- stage A tile (1 uint4/thread) + projw (8 uint4/thread) ----
    {
        int row = t >> 4, ch = t & 15;
        uint4 ra = *(const uint4*)(A + (size_t)(bm+row)*CC + ch*8);
        uint4 rb[8];
        #pragma unroll
        for(int r = 0; r < 8; r++){
            int e = r*256 + t; int rw = e >> 4, c2 = e & 15;
            rb[r] = *(const uint4*)(projw + (size_t)rw*CC + c2*8);
        }
        *(uint4*)&As[row*LDP + ch*8] = ra;
        #pragma unroll
        for(int r = 0; r < 8; r++){
            int e = r*256 + t; int rw = e >> 4, c2 = e & 15;
            *(uint4*)&Bs[rw*LDP + c2*8] = rb[r];
        }
    }
    __syncthreads();

    // ---- proj MFMA: 16 x 128, each wave 2 col-tiles ----
    f32x4 acc[2];
    acc[0] = (f32x4){0.f,0.f,0.f,0.f}; acc[1] = (f32x4){0.f,0.f,0.f,0.f};
    #pragma unroll
    for(int kc = 0; kc < 4; kc++){
        bf16x8 af = *(const bf16x8*)&As[lr*LDP + kc*32 + lg*8];
        #pragma unroll
        for(int j = 0; j < 2; j++){
            bf16x8 bf = *(const bf16x8*)&Bs[(wn + j*16 + lr)*LDP + kc*32 + lg*8];
            acc[j] = __builtin_amdgcn_mfma_f32_16x16x32_bf16(af, bf, acc[j], 0, 0, 0);
        }
    }
    // ---- +bias +residual (registers!), LN stats ----
    float av[2][4];
    #pragma unroll
    for(int reg = 0; reg < 4; reg++){
        int rl = lg*4 + reg;
        float rs_ = 0.f, rq_ = 0.f;
        #pragma unroll
        for(int j = 0; j < 2; j++){
            int col = wn + j*16 + lr;
            float v = acc[j][reg] + u2f(projb[col]) + curin[(size_t)(bm+rl)*CC + col];
            av[j][reg] = v;
            rs_ += v; rq_ += v*v;
        }
        rs_ += __shfl_xor(rs_, 1, 64); rq_ += __shfl_xor(rq_, 1, 64);
        rs_ += __shfl_xor(rs_, 2, 64); rq_ += __shfl_xor(rq_, 2, 64);
        rs_ += __shfl_xor(rs_, 4, 64); rq_ += __shfl_xor(rq_, 4, 64);
        rs_ += __shfl_xor(rs_, 8, 64); rq_ += __shfl_xor(rq_, 8, 64);
        if(lr == 0){ redS[rl][wave] = rs_; redQ[rl][wave] = rq_; }
    }
    __syncthreads();
    if(t < 16){
        float mu = (redS[t][0]+redS[t][1]+redS[t][2]+redS[t][3])*(1.f/CC);
        float var = fmaxf((redQ[t][0]+redQ[t][1]+redQ[t][2]+redQ[t][3])*(1.f/CC) - mu*mu, 0.f);
        muS[t] = mu; rsS[t] = rsqrtf(var + 1e-5f);
    }
    __syncthreads();
    #pragma unroll
    for(int reg = 0; reg < 4; reg++){
        int rl = lg*4 + reg;
        float mu = muS[rl], rstd = rsS[rl];
        #pragma unroll
        for(int j = 0; j < 2; j++){
            int col = wn + j*16 + lr;
            Ls[rl*LDP + col] = f2u((av[j][reg] - mu)*rstd*u2f(lng[col]) + u2f(lnb[col]));
        }
    }

    // ---- fc1: h[16x512] = gelu(ln @ f1w^T + b), stream 8 chunks of 64 rows ----
    for(int nc = 0; nc < 8; nc++){
        uint4 rb[4];
        #pragma unroll
        for(int r = 0; r < 4; r++){
            int e = r*256 + t; int rw = e >> 4, ch = e & 15;
            rb[r] = *(const uint4*)(f1w + (size_t)(nc*64 + rw)*CC + ch*8);
        }
        __syncthreads();                 // previous consumers of Bs (and Ls writes) done
        #pragma unroll
        for(int r = 0; r < 4; r++){
            int e = r*256 + t; int rw = e >> 4, ch = e & 15;
            *(uint4*)&Bs[rw*LDP + ch*8] = rb[r];
        }
        __syncthreads();
        f32x4 a1 = (f32x4){0.f,0.f,0.f,0.f};
        #pragma unroll
        for(int kc = 0; kc < 4; kc++){
            bf16x8 af = *(const bf16x8*)&Ls[lr*LDP + kc*32 + lg*8];
            bf16x8 bf = *(const bf16x8*)&Bs[(wave*16 + lr)*LDP + kc*32 + lg*8];
            a1 = __builtin_amdgcn_mfma_f32_16x16x32_bf16(af, bf, a1, 0, 0, 0);
        }
        #pragma unroll
        for(int reg = 0; reg < 4; reg++){
            int rl = lg*4 + reg;
            int col = nc*64 + wave*16 + lr;
            float v = a1[reg] + u2f(f1b[col]);
            v = 0.5f*v*(1.f + erff(v*0.70710678118f));
            Hs[rl*HSP + col] = f2u(v);
        }
    }

    // ---- fc2: y[16x128] = h @ f2w^T + b + av; stream 4 k-chunks of 128 ----
    f32x4 a2[2];
    a2[0] = (f32x4){0.f,0.f,0.f,0.f}; a2[1] = (f32x4){0.f,0.f,0.f,0.f};
    for(int kc2 = 0; kc2 < 4; kc2++){
        uint4 rb[8];
        #pragma unroll
        for(int r = 0; r < 8; r++){
            int e = r*256 + t; int rw = e >> 4, ch = e & 15;
            rb[r] = *(const uint4*)(f2w + (size_t)rw*HID + kc2*128 + ch*8);
        }
        __syncthreads();                 // previous consumers of Bs (and Hs writes) done
        #pragma unroll
        for(int r = 0; r < 8; r++){
            int e = r*256 + t; int rw = e >> 4, ch = e & 15;
            *(uint4*)&Bs[rw*LDP + ch*8] = rb[r];
        }
        __syncthreads();
        #pragma unroll
        for(int kk = 0; kk < 4; kk++){
            bf16x8 af = *(const bf16x8*)&Hs[lr*HSP + kc2*128 + kk*32 + lg*8];
            #pragma unroll
            for(int j = 0; j < 2; j++){
                bf16x8 bf = *(const bf16x8*)&Bs[(wn + j*16 + lr)*LDP + kk*32 + lg*8];
                a2[j] = __builtin_amdgcn_mfma_f32_16x16x32_bf16(af, bf, a2[j], 0, 0, 0);
            }
        }
    }
    // ---- epilogue: + f2b + av -> curout/cur16, GN stats partial ----
    float ssum = 0.f, sq = 0.f;
    #pragma unroll
    for(int j = 0; j < 2; j++){
        int col = wn + j*16 + lr;
        #pragma unroll
        for(int reg = 0; reg < 4; reg++){
            int row = bm + lg*4 + reg;
            float v = a2[j][reg] + u2f(f2b[col]) + av[j][reg];
            curout[(size_t)row*CC + col] = v;
            cur16[(size_t)row*CC + col] = f2u(v);
            ssum += v; sq += v*v;
        }
    }
    #pragma unroll
    for(int off = 32; off > 0; off >>= 1){
        ssum += __shfl_xor(ssum, off, 64); sq += __shfl_xor(sq, off, 64);
    }
    if(lane == 0){ wred[wave][0] = ssum; wred[wave][1] = sq; }
    __syncthreads();
    if(t == 0){
        gnpart[blockIdx.x*2]   = wred[0][0]+wred[1][0]+wred[2][0]+wred[3][0];
        gnpart[blockIdx.x*2+1] = wred[0][1]+wred[1][1]+wred[2][1]+wred[3][1];
    }
}

// ---------------- fused conv3x3 + c1(ReLU) + c2 + pool (M-tile 32, full N=128) ----------------
__global__ __launch_bounds__(256) void mct_k(
    const u16* __restrict__ in, const u16* __restrict__ Wt, const u16* __restrict__ bias,
    const u16* __restrict__ c1w, const u16* __restrict__ c1b,
    const u16* __restrict__ c2w, const u16* __restrict__ c2b,
    float* __restrict__ ybuf, float* __restrict__ poolacc)
{
    __shared__ __align__(16) u16 As[32*LDP];
    __shared__ __align__(16) u16 Bs[128*LDP];
    u16* Bs1 = Bs;
    u16* Bs2 = Bs + 32*LDP;
    u16* Hs  = Bs + 32*LDP + 128*40;
    const int bm = blockIdx.x*32;
    const int t = threadIdx.x;
    const int wave = t >> 6, lane = t & 63;
    const int wm = (wave >> 1)*16, wn = (wave & 1)*64;
    const int lg = lane >> 4, lr = lane & 15;
    const int nsm = bm >> 12;

    uint4 rb1[2], rb2[2];
    #pragma unroll
    for(int r = 0; r < 2; r++){
        int e = r*256 + t; int row = e >> 4, ch = e & 15;
        rb1[r] = *(const uint4*)(c1w + (size_t)row*CC + ch*8);
    }
    #pragma unroll
    for(int r = 0; r < 2; r++){
        int e = r*256 + t; int row = e >> 2, ch = e & 3;
        rb2[r] = *(const uint4*)(c2w + (size_t)row*C4 + ch*8);
    }

    f32x4 acc[4];
    #pragma unroll
    for(int j = 0; j < 4; j++) acc[j] = (f32x4){0.f,0.f,0.f,0.f};

    for(int tap = 0; tap < 9; tap++){
        int dy = tap/3 - 1, dx = tap%3 - 1;
        uint4 ra[2], rb[8];
        #pragma unroll
        for(int r = 0; r < 2; r++){
            int e = r*256 + t; int row = e >> 4, ch = e & 15;
            int p = bm + row;
            int n = p >> 12, ii = (p & 4095) >> 6, jj = p & 63;
            int y = ii + dy, x = jj + dx;
            ra[r] = (uint4){0,0,0,0};
            if(y >= 0 && y < HH && x >= 0 && x < WW)
                ra[r] = *(const uint4*)(in + (size_t)(((n*HH + y)*WW + x))*CC + ch*8);
        }
        #pragma unroll
        for(int r = 0; r < 8; r++){
            int e = r*256 + t; int row = e >> 4, ch = e & 15;
            rb[r] = *(const uint4*)(Wt + (size_t)row*(9*CC) + tap*128 + ch*8);
        }
        #pragma unroll
        for(int r = 0; r < 2; r++){
            int e = r*256 + t; int row = e >> 4, ch = e & 15;
            *(uint4*)&As[row*LDP + ch*8] = ra[r];
        }
        #pragma unroll
        for(int r = 0; r < 8; r++){
            int e = r*256 + t; int row = e >> 4, ch = e & 15;
            *(uint4*)&Bs[row*LDP + ch*8] = rb[r];
        }
        __syncthreads();
        #pragma unroll
        for(int kc = 0; kc < 4; kc++){
            bf16x8 af = *(const bf16x8*)&As[(wm + lr)*LDP + kc*32 + lg*8];
            #pragma unroll
            for(int j = 0; j < 4; j++){
                bf16x8 bf = *(const bf16x8*)&Bs[(wn + j*16 + lr)*LDP + kc*32 + lg*8];
                acc[j] = __builtin_amdgcn_mfma_f32_16x16x32_bf16(af, bf, acc[j], 0, 0, 0);
            }
        }
        __syncthreads();
    }

    #pragma unroll
    for(int j = 0; j < 4; j++){
        int col = wn + j*16 + lr;
        #pragma unroll
        for(int reg = 0; reg < 4; reg++){
            int rl = wm + lg*4 + reg;
            As[rl*LDP + col] = f2u(acc[j][reg] + u2f(bias[col]));
        }
    }
    #pragma unroll
    for(int r = 0; r < 2; r++){
        int e = r*256 + t; int row = e >> 4, ch = e & 15;
        *(uint4*)&Bs1[row*LDP + ch*8] = rb1[r];
    }
    #pragma unroll
    for(int r = 0; r < 2; r++){
        int e = r*256 + t; int row = e >> 2, ch = e & 3;
        *(uint4*)&Bs2[row*40 + ch*8] = rb2[r];
    }
    __syncthreads();

    {
        const int wn1 = (wave & 1)*16;
        f32x4 a1 = (f32x4){0.f,0.f,0.f,0.f};
        #pragma unroll
        for(int kc = 0; kc < 4; kc++){
            bf16x8 af = *(const bf16x8*)&As[(wm + lr)*LDP + kc*32 + lg*8];
            bf16x8 bf = *(const bf16x8*)&Bs1[(wn1 + lr)*LDP + kc*32 + lg*8];
            a1 = __builtin_amdgcn_mfma_f32_16x16x32_bf16(af, bf, a1, 0, 0, 0);
        }
        #pragma unroll
        for(int reg = 0; reg < 4; reg++){
            int rl = wm + lg*4 + reg;
            int col = wn1 + lr;
            Hs[rl*40 + col] = f2u(fmaxf(a1[reg] + u2f(c1b[col]), 0.f));
        }
    }
    __syncthreads();

    {
        f32x4 a2[4];
        #pragma unroll
        for(int j = 0; j < 4; j++) a2[j] = (f32x4){0.f,0.f,0.f,0.f};
        bf16x8 af = *(const bf16x8*)&Hs[(wm + lr)*40 + lg*8];
        #pragma unroll
        for(int j = 0; j < 4; j++){
            bf16x8 bf = *(const bf16x8*)&Bs2[(wn + j*16 + lr)*40 + lg*8];
            a2[j] = __builtin_amdgcn_mfma_f32_16x16x32_bf16(af, bf, a2[j], 0, 0, 0);
        }
        float cs[4] = {0.f,0.f,0.f,0.f};
        #pragma unroll
        for(int j = 0; j < 4; j++){
            int col = wn + j*16 + lr;
            #pragma unroll
            for(int reg = 0; reg < 4; reg++){
                int row = bm + wm + lg*4 + reg;
                float v = a2[j][reg] + u2f(c2b[col]);
                ybuf[(size_t)row*CC + col] = v;
                cs[j] += v;
            }
        }
        #pragma unroll
        for(int j = 0; j < 4; j++){
            cs[j] += __shfl_xor(cs[j], 16, 64);
            cs[j] += __shfl_xor(cs[j], 32, 64);
        }
        if(lg == 0){
            #pragma unroll
            for(int j = 0; j < 4; j++)
                atomicAdd(&poolacc[nsm*CC + wn + j*16 + lr], cs[j]);
        }
    }
}

// ---------------- MFMA tiled neighborhood attention; P aliased over K-LDS ----------------
#define KVP 72
#define PSP 168

__global__ __launch_bounds__(128) void att_tile_k(
    const u16* __restrict__ qkv, const u16* __restrict__ rpb, u16* __restrict__ out)
{
    __shared__ __align__(16) u16 KV[2][RNB][KVP];
    __shared__ __align__(16) u16 Qs[16][64];
    __shared__ float rpbs[2][169];
    u16* PsB = &KV[0][0][0];
    const int blk = blockIdx.x;
    const int rb = blk >> 1, eg = blk & 1;
    const int p0 = rb*16;
    const int jb = p0 & 63, i = (p0 >> 6) & 63, n = p0 >> 12;
    const int i0 = min(max(i-3, 0), HH-KSZ);
    const int rc0 = min(max(jb-3, 0), WW-KSZ);
    const int t = threadIdx.x;

    for(int idx = t; idx < 2*169; idx += 128)
        rpbs[idx/169][idx%169] = u2f(rpb[(eg*2 + idx/169)*169 + idx%169]);
    {
        int pix = t >> 3, ch = t & 7;
        *(uint4*)&Qs[pix][ch*8] = *(const uint4*)(qkv + (size_t)(p0+pix)*(3*CC) + eg*64 + ch*8);
    }
    for(int idx = t; idx < RNB*16; idx += 128){
        int nb = idx >> 4, part = idx & 15;
        int kv = part >> 3, ch = part & 7;
        uint4 v = (uint4){0,0,0,0};
        if(nb < NBV){
            int ky = nb/RW, kcol = nb - ky*RW;
            int sy = i0 + ky, sx = min(rc0 + kcol, WW-1);
            v = *(const uint4*)(qkv + (size_t)((n*HH + sy)*WW + sx)*(3*CC) + CC + kv*CC + eg*64 + ch*8);
        }
        *(uint4*)&KV[kv][nb][ch*8] = v;
    }
    __syncthreads();

    const int el = t >> 6;
    const int lane = t & 63, lg = lane >> 4, lr = lane & 15;

    bf16x8 aq = *(const bf16x8*)&Qs[lr][el*32 + lg*8];
    f32x4 sc[10];
    #pragma unroll
    for(int c = 0; c < 10; c++){
        bf16x8 bk = *(const bf16x8*)&KV[0][c*16+lr][el*32 + lg*8];
        sc[c] = __builtin_amdgcn_mfma_f32_16x16x32_bf16(aq, bk, (f32x4){0.f,0.f,0.f,0.f}, 0, 0, 0);
    }
    __syncthreads();
    #pragma unroll
    for(int reg = 0; reg < 4; reg++){
        int pix = lg*4 + reg;
        int j = jb + pix;
        int base = min(max(j-3, 0), WW-KSZ) - rc0;
        float mx = -1e30f;
        #pragma unroll
        for(int c = 0; c < 10; c++){
            int nb = c*16 + lr;
            int ky = nb/RW, kcol = nb - ky*RW;
            float v = -1e30f;
            if(nb < NBV && kcol >= base && kcol <= base+6){
                int ri = i0 + ky - i + (KSZ-1);
                int rj = rc0 + kcol - j + (KSZ-1);
                v = sc[c][reg]*0.17677669529663689f + rpbs[el][ri*13 + rj];
            }
            sc[c][reg] = v;
            mx = fmaxf(mx, v);
        }
        mx = fmaxf(mx, __shfl_xor(mx, 1, 64));
        mx = fmaxf(mx, __shfl_xor(mx, 2, 64));
        mx = fmaxf(mx, __shfl_xor(mx, 4, 64));
        mx = fmaxf(mx, __shfl_xor(mx, 8, 64));
        float sum = 0.f;
        #pragma unroll
        for(int c = 0; c < 10; c++){
            float p = __expf(sc[c][reg] - mx);
            sc[c][reg] = p; sum += p;
        }
        sum += __shfl_xor(sum, 1, 64);
        sum += __shfl_xor(sum, 2, 64);
        sum += __shfl_xor(sum, 4, 64);
        sum += __shfl_xor(sum, 8, 64);
        float rs = 1.f/sum;
        #pragma unroll
        for(int c = 0; c < 10; c++)
            PsB[(el*16 + pix)*PSP + c*16 + lr] = f2u(sc[c][reg]*rs);
    }
    __syncthreads();
    f32x4 o0 = (f32x4){0.f,0.f,0.f,0.f}, o1 = (f32x4){0.f,0.f,0.f,0.f};
    #pragma unroll
    for(int ks = 0; ks < 5; ks++){
        bf16x8 ap = *(const bf16x8*)&PsB[(el*16 + lr)*PSP + ks*32 + lg*8];
        bf16x8 b0, b1;
        #pragma unroll
        for(int jj = 0; jj < 8; jj++){
            int nb = ks*32 + lg*8 + jj;
            b0[jj] = (short)KV[1][nb][el*32 + lr];
            b1[jj] = (short)KV[1][nb][el*32 + 16 + lr];
        }
        o0 = __builtin_amdgcn_mfma_f32_16x16x32_bf16(ap, b0, o0, 0, 0, 0);
        o1 = __builtin_amdgcn_mfma_f32_16x16x32_bf16(ap, b1, o1, 0, 0, 0);
    }
    int e = eg*2 + el;
    #pragma unroll
    for(int reg = 0; reg < 4; reg++){
        int pix = lg*4 + reg;
        out[(size_t)(p0+pix)*CC + e*32 + lr]      = f2u(o0[reg]);
        out[(size_t)(p0+pix)*CC + e*32 + 16 + lr] = f2u(o1[reg]);
    }
}

// ---------------- final: inline CA MLP + scale + residual + NCHW store ----------------
__global__ __launch_bounds__(256) void final_ca_k(
    const float* __restrict__ y, const float* __restrict__ poolacc,
    const u16* __restrict__ w1, const u16* __restrict__ b1,
    const u16* __restrict__ w2, const u16* __restrict__ b2,
    const void* __restrict__ xraw, void* __restrict__ outv,
    const int* __restrict__ flag)
{
    __shared__ float t1s[CRED];
    __shared__ float sres;
    int id0 = blockIdx.x*256;
    int c = (id0 >> 12) & (CC-1);
    int n = id0 >> 19;
    int t = threadIdx.x;
    if(t < CRED){
        float a = u2f(b1[t]);
        const float pscale = 1.f/(float)(HH*WW);
        for(int cc = 0; cc < CC; cc++)
            a += poolacc[n*CC + cc]*pscale*u2f(w1[t*CC + cc]);
        t1s[t] = fmaxf(a, 0.f);
    }
    __syncthreads();
    if(t == 0){
        float a = u2f(b2[c]);
        #pragma unroll
        for(int r = 0; r < CRED; r++) a += t1s[r]*u2f(w2[c*CRED + r]);
        sres = 1.f/(1.f + __expf(-a));
    }
    __syncthreads();
    float s = sres;
    int id = id0 + t;
    int j = id & 63; int i = (id >> 6) & 63;
    float xr = (*flag) ? ((const float*)xraw)[id] : u2f(((const u16*)xraw)[id]);
    float v = y[(size_t)((n*HH + i)*WW + j)*CC + c]*s + xr;
    if(*flag) ((float*)outv)[id] = v;
    else      ((u16*)outv)[id] = f2u(v);
}

// ---------------- host ----------------
extern "C" void kernel_launch(void* const* d_in, const int* in_sizes, int n_in,
                              void* d_out, int out_size, void* d_ws, size_t ws_size,
                              hipStream_t stream){
    float* wsf    = (float*)d_ws;
    int*   flagp  = (int*)d_ws;
    float* gnpart = wsf + 8;       // 512*2
    float* poolacc= wsf + 1040;

    u16* Wb = (u16*)(wsf + 2048);
    static const int wsizes[23] = {256,256,98304,768,32768,256,1352,256,256,131072,1024,
                                   131072,256,147456,128,4096,32,4096,128,896,7,896,128};
    int woff[24]; woff[0] = 0;
    for(int i = 0; i < 23; i++) woff[i+1] = woff[i] + wsizes[i];
    const int WTOT = woff[23];
    u16* Wt = Wb + 555760;

    float* AB    = wsf + 360448;
    float* cur   = AB;                                   // f32 residual stream
    u16*  cur16  = (u16*)(AB + 1048576);
    u16*  xg16   = (u16*)(AB + 1572864);                 // attn-out
    u16*  qkv16  = (u16*)(AB + 2097152);
    float* cur2  = AB + 3670016;                         // mlp f32 out (ping-pong with cur)
    float* ybuf  = AB + 2097152;                         // tail y (aliases dead qkv16)

    detect_k<<<1, 256, 0, stream>>>((const u16*)d_in[0], flagp, poolacc);

    PtrTab tab;
    for(int i = 0; i < 23; i++){ tab.p[i] = d_in[i+1]; tab.off[i] = woff[i]; }
    tab.off[23] = woff[23];
    setup_k<<<NCVT + NRPK + NNCH, 256, 0, stream>>>(
        tab, Wb, Wt, d_in[14], d_in[0], cur, gnpart, flagp, WTOT);

    const u16 *gng = Wb+woff[0], *gnb = Wb+woff[1], *qkvw = Wb+woff[2], *qkvb = Wb+woff[3],
              *projw = Wb+woff[4], *projb = Wb+woff[5], *rpbw = Wb+woff[6], *lng = Wb+woff[7],
              *lnb = Wb+woff[8], *f1w = Wb+woff[9], *f1b = Wb+woff[10], *f2w = Wb+woff[11],
              *f2b = Wb+woff[12], *bcb = Wb+woff[14], *c1w = Wb+woff[15],
              *c1b = Wb+woff[16], *c2w = Wb+woff[17], *c2b = Wb+woff[18], *ca1w = Wb+woff[19],
              *ca1b = Wb+woff[20], *ca2w = Wb+woff[21], *ca2b = Wb+woff[22];

    float* rin = cur;
    float* rout = cur2;
    for(int l = 0; l < 2; l++){
        // qkv with fused GN-partial reduce + GN-on-A (gnpart: 256 partials/sample)
        g64_k<EPI_NONE,OUT_BF16,1,EX_NONE><<<dim3(6, PIX/64), 256, 0, stream>>>(
            rin, qkvw + (size_t)l*3*CC*CC, qkvb + l*3*CC, nullptr, nullptr, qkv16,
            gng + l*CC, gnb + l*CC, gnpart, 256, PIX, 3*CC, CC);

        att_tile_k<<<PIX/16*2, 128, 0, stream>>>(qkv16, rpbw + l*NHD*169, xg16);

        // mega-fused MLP: proj+res+LN+fc1+GELU+fc2+res (+ next-layer GN partials)
        mlp_k<<<PIX/16, 256, 0, stream>>>(
            xg16, rin, projw + (size_t)l*CC*CC, projb + l*CC, lng + l*CC, lnb + l*CC,
            f1w + (size_t)l*HID*CC, f1b + l*HID, f2w + (size_t)l*CC*HID, f2b + l*CC,
            rout, cur16, gnpart);

        float* tmp = rin; rin = rout; rout = tmp;
    }

    mct_k<<<PIX/32, 256, 0, stream>>>(cur16, Wt, bcb, c1w, c1b, c2w, c2b, ybuf, poolacc);

    final_ca_k<<<(NN*CC*HH*WW)/256, 256, 0, stream>>>(
        ybuf, poolacc, ca1w, ca1b, ca2w, ca2b, d_in[0], d_out, flagp);
}

// Round 10
// 282.299 us; speedup vs baseline: 1.2608x; 1.2608x over previous
//
#include <hip/hip_runtime.h>
#include <math.h>

typedef unsigned short u16;

#define NN 2
#define CC 128
#define HH 64
#define WW 64
#define NHD 4
#define DH 32
#define KSZ 7
#define PIX (NN*HH*WW)          // 8192
#define HID 512
#define C4 32
#define CRED 7
#define RW 22
#define RNB 160
#define NBV 154

typedef float f32x4 __attribute__((ext_vector_type(4)));
typedef short bf16x8 __attribute__((ext_vector_type(8)));

static __device__ __forceinline__ float u2f(u16 u){ return __uint_as_float(((unsigned)u) << 16); }
static __device__ __forceinline__ u16 f2u(float f){
    unsigned b = __float_as_uint(f);
    return (u16)((b + 0x7FFFu + ((b >> 16) & 1u)) >> 16);
}

// ---------------- dtype sniffer + zero accumulators ----------------
__global__ void detect_k(const u16* __restrict__ x, int* __restrict__ flag,
                         float* __restrict__ poolacc){
    __shared__ float red[256];
    int t = threadIdx.x;
    float mx = 0.f;
    for(int i = t; i < 4096; i += 256){
        float v = fabsf(u2f(x[i]));
        if(v < 1e30f) mx = fmaxf(mx, v);
    }
    red[t] = mx; __syncthreads();
    for(int s = 128; s > 0; s >>= 1){
        if(t < s) red[t] = fmaxf(red[t], red[t+s]);
        __syncthreads();
    }
    if(t == 0) *flag = (red[0] > 1e6f) ? 1 : 0;
    if(t < NN*CC) poolacc[t] = 0.f;
}

// ---------------- combined setup: weight cvt + conv repack + NCHW + GN partials ----------------
struct PtrTab { const void* p[23]; int off[24]; };
#define NCVT 2172
#define NRPK 576
#define NNCH 512

__global__ __launch_bounds__(256) void setup_k(
    PtrTab tab, u16* __restrict__ Wb, u16* __restrict__ Wt,
    const void* __restrict__ convw, const void* __restrict__ x,
    float* __restrict__ cur, float* __restrict__ part,
    const int* __restrict__ flag, int total)
{
    int blk = blockIdx.x;
    int t = threadIdx.x;
    int fl = *flag;
    if(blk < NCVT){
        int i = blk*256 + t;
        if(i < total){
            int a = 0;
            while(i >= tab.off[a+1]) a++;
            int loc = i - tab.off[a];
            Wb[i] = fl ? f2u(((const float*)tab.p[a])[loc]) : ((const u16*)tab.p[a])[loc];
        }
        return;
    }
    if(blk < NCVT + NRPK){
        int i = (blk - NCVT)*256 + t;
        if(i < CC*CC*9){
            int o = i/(9*CC); int rem = i%(9*CC); int tap = rem/CC; int c = rem%CC;
            size_t s = (size_t)(o*CC + c)*9 + tap;
            Wt[i] = fl ? f2u(((const float*)convw)[s]) : ((const u16*)convw)[s];
        }
        return;
    }
    __shared__ float tile[32][65];
    __shared__ float wred[4][2];
    int u = blk - NCVT - NRPK;
    int bx = u & 3, by = u >> 2;
    int n = by >> 6, i = by & 63;
    for(int idx = t; idx < 32*64; idx += 256){
        int cl = idx >> 6, j = idx & 63;
        size_t src = ((size_t)(n*CC + bx*32 + cl)*HH + i)*WW + j;
        tile[cl][j] = fl ? ((const float*)x)[src] : u2f(((const u16*)x)[src]);
    }
    __syncthreads();
    float s = 0.f, q = 0.f;
    for(int idx = t; idx < 64*32; idx += 256){
        int j = idx >> 5, cl = idx & 31;
        float v = tile[cl][j];
        cur[((size_t)((n*HH + i)*WW) + j)*CC + bx*32 + cl] = v;
        s += v; q += v*v;
    }
    #pragma unroll
    for(int off = 32; off > 0; off >>= 1){ s += __shfl_xor(s, off, 64); q += __shfl_xor(q, off, 64); }
    int wave = t >> 6;
    if((t & 63) == 0){ wred[wave][0] = s; wred[wave][1] = q; }
    __syncthreads();
    if(t == 0){
        float ss = wred[0][0]+wred[1][0]+wred[2][0]+wred[3][0];
        float qq = wred[0][1]+wred[1][1]+wred[2][1]+wred[3][1];
        int pidx = n*256 + i*4 + bx;
        part[pidx*2] = ss; part[pidx*2+1] = qq;
    }
}

// ---------------- MFMA GEMM, 64x64 tile, BK=128 (R6/R8-validated) ----------------
enum { EPI_NONE = 0, EPI_RES = 1, EPI_GELU = 2 };
enum { OUT_F32 = 0, OUT_BF16 = 1, OUT_BOTH = 2 };
enum { EX_NONE = 0, EX_STATS = 1 };
#define LDP 136

template<int EPI, int OUTM, int AGN, int EXTRA>
__global__ __launch_bounds__(256) void g64_k(
    const void* __restrict__ Av, const u16* __restrict__ W, const u16* __restrict__ bias,
    const float* __restrict__ R, float* __restrict__ Cf, u16* __restrict__ Cb,
    const u16* __restrict__ gnw, const u16* __restrict__ gnb,
    float* __restrict__ gnpart, int gncount,
    int M, int N, int K)
{
    __shared__ __align__(16) u16 As[64*LDP];
    __shared__ __align__(16) u16 Bs[64*LDP];
    __shared__ float wred[4][2];
    const int bm = blockIdx.y*64, bn = blockIdx.x*64;
    const int t = threadIdx.x;
    const int wave = t >> 6, lane = t & 63;
    const int wm = (wave >> 1)*32, wn = (wave & 1)*32;
    const int lg = lane >> 4, lr = lane & 15;
    const int nsm = bm >> 12;
    f32x4 acc[2][2];
    #pragma unroll
    for(int i = 0; i < 2; i++)
        #pragma unroll
        for(int j = 0; j < 2; j++) acc[i][j] = (f32x4){0.f,0.f,0.f,0.f};

    float gmu = 0.f, grs = 0.f;
    if(AGN){
        float a = 0.f, q = 0.f;
        for(int idx = lane; idx < gncount; idx += 64){
            a += gnpart[(nsm*gncount + idx)*2];
            q += gnpart[(nsm*gncount + idx)*2 + 1];
        }
        #pragma unroll
        for(int off = 32; off > 0; off >>= 1){
            a += __shfl_xor(a, off, 64); q += __shfl_xor(q, off, 64);
        }
        const float inv = 1.f/(float)(HH*WW*CC);
        gmu = a*inv;
        grs = rsqrtf(fmaxf(q*inv - gmu*gmu, 0.f) + 1e-5f);
    }

    for(int k0 = 0; k0 < K; k0 += 128){
        uint4 ra[4], rb[4];
        float4 fa[4][2];
        #pragma unroll
        for(int r = 0; r < 4; r++){
            int e = r*256 + t;
            int row = e >> 4, ch = e & 15;
            if(AGN){
                const float* ap = (const float*)Av + (size_t)(bm+row)*K + k0 + ch*8;
                fa[r][0] = *(const float4*)ap;
                fa[r][1] = *(const float4*)(ap + 4);
            } else {
                ra[r] = *(const uint4*)((const u16*)Av + (size_t)(bm+row)*K + k0 + ch*8);
            }
            rb[r] = (bn+row < N) ? *(const uint4*)(W + (size_t)(bn+row)*K + k0 + ch*8)
                                 : (uint4){0,0,0,0};
        }
        #pragma unroll
        for(int r = 0; r < 4; r++){
            int e = r*256 + t;
            int row = e >> 4, ch = e & 15;
            if(AGN){
                union { uint4 u; u16 h[8]; } g8, b8, o8;
                g8.u = *(const uint4*)(gnw + k0 + ch*8);
                b8.u = *(const uint4*)(gnb + k0 + ch*8);
                const float* fv = (const float*)&fa[r][0];
                #pragma unroll
                for(int z = 0; z < 8; z++)
                    o8.h[z] = f2u((fv[z]-gmu)*grs*u2f(g8.h[z]) + u2f(b8.h[z]));
                *(uint4*)&As[row*LDP + ch*8] = o8.u;
            } else {
                *(uint4*)&As[row*LDP + ch*8] = ra[r];
            }
            *(uint4*)&Bs[row*LDP + ch*8] = rb[r];
        }
        __syncthreads();
        #pragma unroll
        for(int kc = 0; kc < 4; kc++){
            bf16x8 af0 = *(const bf16x8*)&As[(wm + lr)*LDP      + kc*32 + lg*8];
            bf16x8 af1 = *(const bf16x8*)&As[(wm + 16 + lr)*LDP + kc*32 + lg*8];
            bf16x8 bf0 = *(const bf16x8*)&Bs[(wn + lr)*LDP      + kc*32 + lg*8];
            bf16x8 bf1 = *(const bf16x8*)&Bs[(wn + 16 + lr)*LDP + kc*32 + lg*8];
            acc[0][0] = __builtin_amdgcn_mfma_f32_16x16x32_bf16(af0, bf0, acc[0][0], 0, 0, 0);
            acc[0][1] = __builtin_amdgcn_mfma_f32_16x16x32_bf16(af0, bf1, acc[0][1], 0, 0, 0);
            acc[1][0] = __builtin_amdgcn_mfma_f32_16x16x32_bf16(af1, bf0, acc[1][0], 0, 0, 0);
            acc[1][1] = __builtin_amdgcn_mfma_f32_16x16x32_bf16(af1, bf1, acc[1][1], 0, 0, 0);
        }
        if(k0 + 128 < K) __syncthreads();
    }

    float ssum = 0.f, sq = 0.f;
    #pragma unroll
    for(int i = 0; i < 2; i++){
        #pragma unroll
        for(int j = 0; j < 2; j++){
            int col = bn + wn + j*16 + lr;
            if(col >= N) continue;
            #pragma unroll
            for(int reg = 0; reg < 4; reg++){
                int row = bm + wm + i*16 + lg*4 + reg;
                float v = acc[i][j][reg] + u2f(bias[col]);
                if(EPI == EPI_RES)  v += R[(size_t)row*N + col];
                if(EPI == EPI_GELU) v = 0.5f*v*(1.f + erff(v*0.70710678118f));
                if(OUTM == OUT_F32 || OUTM == OUT_BOTH) Cf[(size_t)row*N + col] = v;
                if(OUTM == OUT_BF16 || OUTM == OUT_BOTH) Cb[(size_t)row*N + col] = f2u(v);
                if(EXTRA == EX_STATS){ ssum += v; sq += v*v; }
            }
        }
    }
    if(EXTRA == EX_STATS){
        #pragma unroll
        for(int off = 32; off > 0; off >>= 1){
            ssum += __shfl_xor(ssum, off, 64); sq += __shfl_xor(sq, off, 64);
        }
        if(lane == 0){ wred[wave][0] = ssum; wred[wave][1] = sq; }
        __syncthreads();
        if(t == 0){
            int bidx = blockIdx.y*gridDim.x + blockIdx.x;
            gnpart[bidx*2]   = wred[0][0]+wred[1][0]+wred[2][0]+wred[3][0];
            gnpart[bidx*2+1] = wred[0][1]+wred[1][1]+wred[2][1]+wred[3][1];
        }
    }
}

// ---------------- proj + residual + LayerNorm fused (M-tile 16; R9-validated logic) ----------------
__global__ __launch_bounds__(256) void proj_ln_k(
    const u16* __restrict__ A, const u16* __restrict__ W, const u16* __restrict__ bias,
    const float* __restrict__ R, const u16* __restrict__ lng, const u16* __restrict__ lnb,
    float* __restrict__ abuf, u16* __restrict__ lnout)
{
    __shared__ __align__(16) u16 As[16*LDP];
    __shared__ __align__(16) u16 Bs[128*LDP];
    __shared__ float redS[16][4], redQ[16][4], muS[16], rsS[16];
    const int bm = blockIdx.x*16;
    const int t = threadIdx.x;
    const int wave = t >> 6, lane = t & 63;
    const int wn = wave*32;                      // each wave: 16 rows x 32 cols
    const int lg = lane >> 4, lr = lane & 15;

    {
        int row = t >> 4, ch = t & 15;
        uint4 ra = *(const uint4*)(A + (size_t)(bm+row)*CC + ch*8);
        uint4 rb[8];
        #pragma unroll
        for(int r = 0; r < 8; r++){
            int e = r*256 + t; int rw = e >> 4, c2 = e & 15;
            rb[r] = *(const uint4*)(W + (size_t)rw*CC + c2*8);
        }
        *(uint4*)&As[row*LDP + ch*8] = ra;
        #pragma unroll
        for(int r = 0; r < 8; r++){
            int e = r*256 + t; int rw = e >> 4, c2 = e & 15;
            *(uint4*)&Bs[rw*LDP + c2*8] = rb[r];
        }
    }
    __syncthreads();

    f32x4 acc[2];
    acc[0] = (f32x4){0.f,0.f,0.f,0.f}; acc[1] = (f32x4){0.f,0.f,0.f,0.f};
    #pragma unroll
    for(int kc = 0; kc < 4; kc++){
        bf16x8 af = *(const bf16x8*)&As[lr*LDP + kc*32 + lg*8];
        #pragma unroll
        for(int j = 0; j < 2; j++){
            bf16x8 bf = *(const bf16x8*)&Bs[(wn + j*16 + lr)*LDP + kc*32 + lg*8];
            acc[j] = __builtin_amdgcn_mfma_f32_16x16x32_bf16(af, bf, acc[j], 0, 0, 0);
        }
    }
    float av[2][4];
    #pragma unroll
    for(int reg = 0; reg < 4; reg++){
        int rl = lg*4 + reg;
        float rs_ = 0.f, rq_ = 0.f;
        #pragma unroll
        for(int j = 0; j < 2; j++){
            int col = wn + j*16 + lr;
            float v = acc[j][reg] + u2f(bias[col]) + R[(size_t)(bm+rl)*CC + col];
            av[j][reg] = v;
            abuf[(size_t)(bm+rl)*CC + col] = v;
            rs_ += v; rq_ += v*v;
        }
        rs_ += __shfl_xor(rs_, 1, 64); rq_ += __shfl_xor(rq_, 1, 64);
        rs_ += __shfl_xor(rs_, 2, 64); rq_ += __shfl_xor(rq_, 2, 64);
        rs_ += __shfl_xor(rs_, 4, 64); rq_ += __shfl_xor(rq_, 4, 64);
        rs_ += __shfl_xor(rs_, 8, 64); rq_ += __shfl_xor(rq_, 8, 64);
        if(lr == 0){ redS[rl][wave] = rs_; redQ[rl][wave] = rq_; }
    }
    __syncthreads();
    if(t < 16){
        float mu = (redS[t][0]+redS[t][1]+redS[t][2]+redS[t][3])*(1.f/CC);
        float var = fmaxf((redQ[t][0]+redQ[t][1]+redQ[t][2]+redQ[t][3])*(1.f/CC) - mu*mu, 0.f);
        muS[t] = mu; rsS[t] = rsqrtf(var + 1e-5f);
    }
    __syncthreads();
    #pragma unroll
    for(int reg = 0; reg < 4; reg++){
        int rl = lg*4 + reg;
        float mu = muS[rl], rstd = rsS[rl];
        #pragma unroll
        for(int j = 0; j < 2; j++){
            int col = wn + j*16 + lr;
            float v = (av[j][reg] - mu)*rstd*u2f(lng[col]) + u2f(lnb[col]);
            lnout[(size_t)(bm+rl)*CC + col] = f2u(v);
        }
    }
}

// ---------------- fused conv3x3 + c1(ReLU) + c2 + pool (R8-validated) ----------------
__global__ __launch_bounds__(256) void mct_k(
    const u16* __restrict__ in, const u16* __restrict__ Wt, const u16* __restrict__ bias,
    const u16* __restrict__ c1w, const u16* __restrict__ c1b,
    const u16* __restrict__ c2w, const u16* __restrict__ c2b,
    float* __restrict__ ybuf, float* __restrict__ poolacc)
{
    __shared__ __align__(16) u16 As[32*LDP];
    __shared__ __align__(16) u16 Bs[128*LDP];
    u16* Bs1 = Bs;
    u16* Bs2 = Bs + 32*LDP;
    u16* Hs  = Bs + 32*LDP + 128*40;
    const int bm = blockIdx.x*32;
    const int t = threadIdx.x;
    const int wave = t >> 6, lane = t & 63;
    const int wm = (wave >> 1)*16, wn = (wave & 1)*64;
    const int lg = lane >> 4, lr = lane & 15;
    const int nsm = bm >> 12;

    uint4 rb1[2], rb2[2];
    #pragma unroll
    for(int r = 0; r < 2; r++){
        int e = r*256 + t; int row = e >> 4, ch = e & 15;
        rb1[r] = *(const uint4*)(c1w + (size_t)row*CC + ch*8);
    }
    #pragma unroll
    for(int r = 0; r < 2; r++){
        int e = r*256 + t; int row = e >> 2, ch = e & 3;
        rb2[r] = *(const uint4*)(c2w + (size_t)row*C4 + ch*8);
    }

    f32x4 acc[4];
    #pragma unroll
    for(int j = 0; j < 4; j++) acc[j] = (f32x4){0.f,0.f,0.f,0.f};

    for(int tap = 0; tap < 9; tap++){
        int dy = tap/3 - 1, dx = tap%3 - 1;
        uint4 ra[2], rb[8];
        #pragma unroll
        for(int r = 0; r < 2; r++){
            int e = r*256 + t; int row = e >> 4, ch = e & 15;
            int p = bm + row;
            int n = p >> 12, ii = (p & 4095) >> 6, jj = p & 63;
            int y = ii + dy, x = jj + dx;
            ra[r] = (uint4){0,0,0,0};
            if(y >= 0 && y < HH && x >= 0 && x < WW)
                ra[r] = *(const uint4*)(in + (size_t)(((n*HH + y)*WW + x))*CC + ch*8);
        }
        #pragma unroll
        for(int r = 0; r < 8; r++){
            int e = r*256 + t; int row = e >> 4, ch = e & 15;
            rb[r] = *(const uint4*)(Wt + (size_t)row*(9*CC) + tap*128 + ch*8);
        }
        #pragma unroll
        for(int r = 0; r < 2; r++){
            int e = r*256 + t; int row = e >> 4, ch = e & 15;
            *(uint4*)&As[row*LDP + ch*8] = ra[r];
        }
        #pragma unroll
        for(int r = 0; r < 8; r++){
            int e = r*256 + t; int row = e >> 4, ch = e & 15;
            *(uint4*)&Bs[row*LDP + ch*8] = rb[r];
        }
        __syncthreads();
        #pragma unroll
        for(int kc = 0; kc < 4; kc++){
            bf16x8 af = *(const bf16x8*)&As[(wm + lr)*LDP + kc*32 + lg*8];
            #pragma unroll
            for(int j = 0; j < 4; j++){
                bf16x8 bf = *(const bf16x8*)&Bs[(wn + j*16 + lr)*LDP + kc*32 + lg*8];
                acc[j] = __builtin_amdgcn_mfma_f32_16x16x32_bf16(af, bf, acc[j], 0, 0, 0);
            }
        }
        __syncthreads();
    }

    #pragma unroll
    for(int j = 0; j < 4; j++){
        int col = wn + j*16 + lr;
        #pragma unroll
        for(int reg = 0; reg < 4; reg++){
            int rl = wm + lg*4 + reg;
            As[rl*LDP + col] = f2u(acc[j][reg] + u2f(bias[col]));
        }
    }
    #pragma unroll
    for(int r = 0; r < 2; r++){
        int e = r*256 + t; int row = e >> 4, ch = e & 15;
        *(uint4*)&Bs1[row*LDP + ch*8] = rb1[r];
    }
    #pragma unroll
    for(int r = 0; r < 2; r++){
        int e = r*256 + t; int row = e >> 2, ch = e & 3;
        *(uint4*)&Bs2[row*40 + ch*8] = rb2[r];
    }
    __syncthreads();

    {
        const int wn1 = (wave & 1)*16;
        f32x4 a1 = (f32x4){0.f,0.f,0.f,0.f};
        #pragma unroll
        for(int kc = 0; kc < 4; kc++){
            bf16x8 af = *(const bf16x8*)&As[(wm + lr)*LDP + kc*32 + lg*8];
            bf16x8 bf = *(const bf16x8*)&Bs1[(wn1 + lr)*LDP + kc*32 + lg*8];
            a1 = __builtin_amdgcn_mfma_f32_16x16x32_bf16(af, bf, a1, 0, 0, 0);
        }
        #pragma unroll
        for(int reg = 0; reg < 4; reg++){
            int rl = wm + lg*4 + reg;
            int col = wn1 + lr;
            Hs[rl*40 + col] = f2u(fmaxf(a1[reg] + u2f(c1b[col]), 0.f));
        }
    }
    __syncthreads();

    {
        f32x4 a2[4];
        #pragma unroll
        for(int j = 0; j < 4; j++) a2[j] = (f32x4){0.f,0.f,0.f,0.f};
        bf16x8 af = *(const bf16x8*)&Hs[(wm + lr)*40 + lg*8];
        #pragma unroll
        for(int j = 0; j < 4; j++){
            bf16x8 bf = *(const bf16x8*)&Bs2[(wn + j*16 + lr)*40 + lg*8];
            a2[j] = __builtin_amdgcn_mfma_f32_16x16x32_bf16(af, bf, a2[j], 0, 0, 0);
        }
        float cs[4] = {0.f,0.f,0.f,0.f};
        #pragma unroll
        for(int j = 0; j < 4; j++){
            int col = wn + j*16 + lr;
            #pragma unroll
            for(int reg = 0; reg < 4; reg++){
                int row = bm + wm + lg*4 + reg;
                float v = a2[j][reg] + u2f(c2b[col]);
                ybuf[(size_t)row*CC + col] = v;
                cs[j] += v;
            }
        }
        #pragma unroll
        for(int j = 0; j < 4; j++){
            cs[j] += __shfl_xor(cs[j], 16, 64);
            cs[j] += __shfl_xor(cs[j], 32, 64);
        }
        if(lg == 0){
            #pragma unroll
            for(int j = 0; j < 4; j++)
                atomicAdd(&poolacc[nsm*CC + wn + j*16 + lr], cs[j]);
        }
    }
}

// ---------------- MFMA tiled neighborhood attention; P aliased over K-LDS ----------------
#define KVP 72
#define PSP 168

__global__ __launch_bounds__(128) void att_tile_k(
    const u16* __restrict__ qkv, const u16* __restrict__ rpb, u16* __restrict__ out)
{
    __shared__ __align__(16) u16 KV[2][RNB][KVP];
    __shared__ __align__(16) u16 Qs[16][64];
    __shared__ float rpbs[2][169];
    u16* PsB = &KV[0][0][0];
    const int blk = blockIdx.x;
    const int rb = blk >> 1, eg = blk & 1;
    const int p0 = rb*16;
    const int jb = p0 & 63, i = (p0 >> 6) & 63, n = p0 >> 12;
    const int i0 = min(max(i-3, 0), HH-KSZ);
    const int rc0 = min(max(jb-3, 0), WW-KSZ);
    const int t = threadIdx.x;

    for(int idx = t; idx < 2*169; idx += 128)
        rpbs[idx/169][idx%169] = u2f(rpb[(eg*2 + idx/169)*169 + idx%169]);
    {
        int pix = t >> 3, ch = t & 7;
        *(uint4*)&Qs[pix][ch*8] = *(const uint4*)(qkv + (size_t)(p0+pix)*(3*CC) + eg*64 + ch*8);
    }
    for(int idx = t; idx < RNB*16; idx += 128){
        int nb = idx >> 4, part = idx & 15;
        int kv = part >> 3, ch = part & 7;
        uint4 v = (uint4){0,0,0,0};
        if(nb < NBV){
            int ky = nb/RW, kcol = nb - ky*RW;
            int sy = i0 + ky, sx = min(rc0 + kcol, WW-1);
            v = *(const uint4*)(qkv + (size_t)((n*HH + sy)*WW + sx)*(3*CC) + CC + kv*CC + eg*64 + ch*8);
        }
        *(uint4*)&KV[kv][nb][ch*8] = v;
    }
    __syncthreads();

    const int el = t >> 6;
    const int lane = t & 63, lg = lane >> 4, lr = lane & 15;

    bf16x8 aq = *(const bf16x8*)&Qs[lr][el*32 + lg*8];
    f32x4 sc[10];
    #pragma unroll
    for(int c = 0; c < 10; c++){
        bf16x8 bk = *(const bf16x8*)&KV[0][c*16+lr][el*32 + lg*8];
        sc[c] = __builtin_amdgcn_mfma_f32_16x16x32_bf16(aq, bk, (f32x4){0.f,0.f,0.f,0.f}, 0, 0, 0);
    }
    __syncthreads();
    #pragma unroll
    for(int reg = 0; reg < 4; reg++){
        int pix = lg*4 + reg;
        int j = jb + pix;
        int base = min(max(j-3, 0), WW-KSZ) - rc0;
        float mx = -1e30f;
        #pragma unroll
        for(int c = 0; c < 10; c++){
            int nb = c*16 + lr;
            int ky = nb/RW, kcol = nb - ky*RW;
            float v = -1e30f;
            if(nb < NBV && kcol >= base && kcol <= base+6){
                int ri = i0 + ky - i + (KSZ-1);
                int rj = rc0 + kcol - j + (KSZ-1);
                v = sc[c][reg]*0.17677669529663689f + rpbs[el][ri*13 + rj];
            }
            sc[c][reg] = v;
            mx = fmaxf(mx, v);
        }
        mx = fmaxf(mx, __shfl_xor(mx, 1, 64));
        mx = fmaxf(mx, __shfl_xor(mx, 2, 64));
        mx = fmaxf(mx, __shfl_xor(mx, 4, 64));
        mx = fmaxf(mx, __shfl_xor(mx, 8, 64));
        float sum = 0.f;
        #pragma unroll
        for(int c = 0; c < 10; c++){
            float p = __expf(sc[c][reg] - mx);
            sc[c][reg] = p; sum += p;
        }
        sum += __shfl_xor(sum, 1, 64);
        sum += __shfl_xor(sum, 2, 64);
        sum += __shfl_xor(sum, 4, 64);
        sum += __shfl_xor(sum, 8, 64);
        float rs = 1.f/sum;
        #pragma unroll
        for(int c = 0; c < 10; c++)
            PsB[(el*16 + pix)*PSP + c*16 + lr] = f2u(sc[c][reg]*rs);
    }
    __syncthreads();
    f32x4 o0 = (f32x4){0.f,0.f,0.f,0.f}, o1 = (f32x4){0.f,0.f,0.f,0.f};
    #pragma unroll
    for(int ks = 0; ks < 5; ks++){
        bf16x8 ap = *(const bf16x8*)&PsB[(el*16 + lr)*PSP + ks*32 + lg*8];
        bf16x8 b0, b1;
        #pragma unroll
        for(int jj = 0; jj < 8; jj++){
            int nb = ks*32 + lg*8 + jj;
            b0[jj] = (short)KV[1][nb][el*32 + lr];
            b1[jj] = (short)KV[1][nb][el*32 + 16 + lr];
        }
        o0 = __builtin_amdgcn_mfma_f32_16x16x32_bf16(ap, b0, o0, 0, 0, 0);
        o1 = __builtin_amdgcn_mfma_f32_16x16x32_bf16(ap, b1, o1, 0, 0, 0);
    }
    int e = eg*2 + el;
    #pragma unroll
    for(int reg = 0; reg < 4; reg++){
        int pix = lg*4 + reg;
        out[(size_t)(p0+pix)*CC + e*32 + lr]      = f2u(o0[reg]);
        out[(size_t)(p0+pix)*CC + e*32 + 16 + lr] = f2u(o1[reg]);
    }
}

// ---------------- final: inline CA MLP + scale + residual + NCHW store ----------------
__global__ __launch_bounds__(256) void final_ca_k(
    const float* __restrict__ y, const float* __restrict__ poolacc,
    const u16* __restrict__ w1, const u16* __restrict__ b1,
    const u16* __restrict__ w2, const u16* __restrict__ b2,
    const void* __restrict__ xraw, void* __restrict__ outv,
    const int* __restrict__ flag)
{
    __shared__ float t1s[CRED];
    __shared__ float sres;
    int id0 = blockIdx.x*256;
    int c = (id0 >> 12) & (CC-1);
    int n = id0 >> 19;
    int t = threadIdx.x;
    if(t < CRED){
        float a = u2f(b1[t]);
        const float pscale = 1.f/(float)(HH*WW);
        for(int cc = 0; cc < CC; cc++)
            a += poolacc[n*CC + cc]*pscale*u2f(w1[t*CC + cc]);
        t1s[t] = fmaxf(a, 0.f);
    }
    __syncthreads();
    if(t == 0){
        float a = u2f(b2[c]);
        #pragma unroll
        for(int r = 0; r < CRED; r++) a += t1s[r]*u2f(w2[c*CRED + r]);
        sres = 1.f/(1.f + __expf(-a));
    }
    __syncthreads();
    float s = sres;
    int id = id0 + t;
    int j = id & 63; int i = (id >> 6) & 63;
    float xr = (*flag) ? ((const float*)xraw)[id] : u2f(((const u16*)xraw)[id]);
    float v = y[(size_t)((n*HH + i)*WW + j)*CC + c]*s + xr;
    if(*flag) ((float*)outv)[id] = v;
    else      ((u16*)outv)[id] = f2u(v);
}

// ---------------- host ----------------
extern "C" void kernel_launch(void* const* d_in, const int* in_sizes, int n_in,
                              void* d_out, int out_size, void* d_ws, size_t ws_size,
                              hipStream_t stream){
    float* wsf    = (float*)d_ws;
    int*   flagp  = (int*)d_ws;
    float* gnpart = wsf + 8;
    float* poolacc= wsf + 1040;

    u16* Wb = (u16*)(wsf + 2048);
    static const int wsizes[23] = {256,256,98304,768,32768,256,1352,256,256,131072,1024,
                                   131072,256,147456,128,4096,32,4096,128,896,7,896,128};
    int woff[24]; woff[0] = 0;
    for(int i = 0; i < 23; i++) woff[i+1] = woff[i] + wsizes[i];
    const int WTOT = woff[23];
    u16* Wt = Wb + 555760;

    float* AB    = wsf + 360448;
    float* cur   = AB;                                   // f32 residual stream
    u16*  cur16  = (u16*)(AB + 1048576);
    u16*  xg16   = (u16*)(AB + 1572864);                 // attn-out / ln-out
    u16*  qkv16  = (u16*)(AB + 2097152);
    float* abuf  = AB + 2097152;                         // aliases qkv16 (dead after att)
    u16*  hbuf16 = (u16*)(AB + 3670016);
    float* ybuf  = AB + 3670016;                         // aliases hbuf16 (dead after fc2)

    detect_k<<<1, 256, 0, stream>>>((const u16*)d_in[0], flagp, poolacc);

    PtrTab tab;
    for(int i = 0; i < 23; i++){ tab.p[i] = d_in[i+1]; tab.off[i] = woff[i]; }
    tab.off[23] = woff[23];
    setup_k<<<NCVT + NRPK + NNCH, 256, 0, stream>>>(
        tab, Wb, Wt, d_in[14], d_in[0], cur, gnpart, flagp, WTOT);

    const u16 *gng = Wb+woff[0], *gnb = Wb+woff[1], *qkvw = Wb+woff[2], *qkvb = Wb+woff[3],
              *projw = Wb+woff[4], *projb = Wb+woff[5], *rpbw = Wb+woff[6], *lng = Wb+woff[7],
              *lnb = Wb+woff[8], *f1w = Wb+woff[9], *f1b = Wb+woff[10], *f2w = Wb+woff[11],
              *f2b = Wb+woff[12], *bcb = Wb+woff[14], *c1w = Wb+woff[15],
              *c1b = Wb+woff[16], *c2w = Wb+woff[17], *c2b = Wb+woff[18], *ca1w = Wb+woff[19],
              *ca1b = Wb+woff[20], *ca2w = Wb+woff[21], *ca2b = Wb+woff[22];

    for(int l = 0; l < 2; l++){
        int gncount = (l == 0) ? 256 : 128;

        g64_k<EPI_NONE,OUT_BF16,1,EX_NONE><<<dim3(6, PIX/64), 256, 0, stream>>>(
            cur, qkvw + (size_t)l*3*CC*CC, qkvb + l*3*CC, nullptr, nullptr, qkv16,
            gng + l*CC, gnb + l*CC, gnpart, gncount, PIX, 3*CC, CC);

        att_tile_k<<<PIX/16*2, 128, 0, stream>>>(qkv16, rpbw + l*NHD*169, xg16);

        proj_ln_k<<<PIX/16, 256, 0, stream>>>(
            xg16, projw + (size_t)l*CC*CC, projb + l*CC, cur, lng + l*CC, lnb + l*CC,
            abuf, xg16);

        g64_k<EPI_GELU,OUT_BF16,0,EX_NONE><<<dim3(8, PIX/64), 256, 0, stream>>>(
            xg16, f1w + (size_t)l*HID*CC, f1b + l*HID, nullptr, nullptr, hbuf16,
            nullptr, nullptr, nullptr, 0, PIX, HID, CC);

        g64_k<EPI_RES,OUT_BOTH,0,EX_STATS><<<dim3(2, PIX/64), 256, 0, stream>>>(
            hbuf16, f2w + (size_t)l*CC*HID, f2b + l*CC, abuf, cur, cur16,
            nullptr, nullptr, gnpart, 0, PIX, CC, HID);
    }

    mct_k<<<PIX/32, 256, 0, stream>>>(cur16, Wt, bcb, c1w, c1b, c2w, c2b, ybuf, poolacc);

    final_ca_k<<<(NN*CC*HH*WW)/256, 256, 0, stream>>>(
        ybuf, poolacc, ca1w, ca1b, ca2w, ca2b, d_in[0], d_out, flagp);
}

// Round 11
// 263.385 us; speedup vs baseline: 1.3513x; 1.0718x over previous
//
#include <hip/hip_runtime.h>
#include <math.h>

typedef unsigned short u16;

#define NN 2
#define CC 128
#define HH 64
#define WW 64
#define NHD 4
#define DH 32
#define KSZ 7
#define PIX (NN*HH*WW)          // 8192
#define HID 512
#define C4 32
#define CRED 7
#define RW 22
#define RNB 160
#define NBV 154

typedef float f32x4 __attribute__((ext_vector_type(4)));
typedef short bf16x8 __attribute__((ext_vector_type(8)));

static __device__ __forceinline__ float u2f(u16 u){ return __uint_as_float(((unsigned)u) << 16); }
static __device__ __forceinline__ u16 f2u(float f){
    unsigned b = __float_as_uint(f);
    return (u16)((b + 0x7FFFu + ((b >> 16) & 1u)) >> 16);
}

// ---------------- dtype sniffer + zero accumulators ----------------
__global__ void detect_k(const u16* __restrict__ x, int* __restrict__ flag,
                         float* __restrict__ poolacc){
    __shared__ float red[256];
    int t = threadIdx.x;
    float mx = 0.f;
    for(int i = t; i < 4096; i += 256){
        float v = fabsf(u2f(x[i]));
        if(v < 1e30f) mx = fmaxf(mx, v);
    }
    red[t] = mx; __syncthreads();
    for(int s = 128; s > 0; s >>= 1){
        if(t < s) red[t] = fmaxf(red[t], red[t+s]);
        __syncthreads();
    }
    if(t == 0) *flag = (red[0] > 1e6f) ? 1 : 0;
    if(t < NN*CC) poolacc[t] = 0.f;
}

// ---------------- combined setup: weight cvt + conv repack + NCHW + GN partials ----------------
struct PtrTab { const void* p[23]; int off[24]; };
#define NCVT 2172
#define NRPK 576
#define NNCH 512

__global__ __launch_bounds__(256) void setup_k(
    PtrTab tab, u16* __restrict__ Wb, u16* __restrict__ Wt,
    const void* __restrict__ convw, const void* __restrict__ x,
    float* __restrict__ cur, float* __restrict__ part,
    const int* __restrict__ flag, int total)
{
    int blk = blockIdx.x;
    int t = threadIdx.x;
    int fl = *flag;
    if(blk < NCVT){
        int i = blk*256 + t;
        if(i < total){
            int a = 0;
            while(i >= tab.off[a+1]) a++;
            int loc = i - tab.off[a];
            Wb[i] = fl ? f2u(((const float*)tab.p[a])[loc]) : ((const u16*)tab.p[a])[loc];
        }
        return;
    }
    if(blk < NCVT + NRPK){
        int i = (blk - NCVT)*256 + t;
        if(i < CC*CC*9){
            int o = i/(9*CC); int rem = i%(9*CC); int tap = rem/CC; int c = rem%CC;
            size_t s = (size_t)(o*CC + c)*9 + tap;
            Wt[i] = fl ? f2u(((const float*)convw)[s]) : ((const u16*)convw)[s];
        }
        return;
    }
    __shared__ float tile[32][65];
    __shared__ float wred[4][2];
    int u = blk - NCVT - NRPK;
    int bx = u & 3, by = u >> 2;
    int n = by >> 6, i = by & 63;
    for(int idx = t; idx < 32*64; idx += 256){
        int cl = idx >> 6, j = idx & 63;
        size_t src = ((size_t)(n*CC + bx*32 + cl)*HH + i)*WW + j;
        tile[cl][j] = fl ? ((const float*)x)[src] : u2f(((const u16*)x)[src]);
    }
    __syncthreads();
    float s = 0.f, q = 0.f;
    for(int idx = t; idx < 64*32; idx += 256){
        int j = idx >> 5, cl = idx & 31;
        float v = tile[cl][j];
        cur[((size_t)((n*HH + i)*WW) + j)*CC + bx*32 + cl] = v;
        s += v; q += v*v;
    }
    #pragma unroll
    for(int off = 32; off > 0; off >>= 1){ s += __shfl_xor(s, off, 64); q += __shfl_xor(q, off, 64); }
    int wave = t >> 6;
    if((t & 63) == 0){ wred[wave][0] = s; wred[wave][1] = q; }
    __syncthreads();
    if(t == 0){
        float ss = wred[0][0]+wred[1][0]+wred[2][0]+wred[3][0];
        float qq = wred[0][1]+wred[1][1]+wred[2][1]+wred[3][1];
        int pidx = n*256 + i*4 + bx;
        part[pidx*2] = ss; part[pidx*2+1] = qq;
    }
}

// ---------------- MFMA GEMM, 64x64 tile, BK=128 (R6/R8-validated) ----------------
enum { EPI_NONE = 0, EPI_RES = 1, EPI_GELU = 2 };
enum { OUT_F32 = 0, OUT_BF16 = 1, OUT_BOTH = 2 };
enum { EX_NONE = 0, EX_STATS = 1 };
#define LDP 136

template<int EPI, int OUTM, int AGN, int EXTRA>
__global__ __launch_bounds__(256) void g64_k(
    const void* __restrict__ Av, const u16* __restrict__ W, const u16* __restrict__ bias,
    const float* __restrict__ R, float* __restrict__ Cf, u16* __restrict__ Cb,
    const u16* __restrict__ gnw, const u16* __restrict__ gnb,
    float* __restrict__ gnpart, int gncount,
    int M, int N, int K)
{
    __shared__ __align__(16) u16 As[64*LDP];
    __shared__ __align__(16) u16 Bs[64*LDP];
    __shared__ float wred[4][2];
    const int bm = blockIdx.y*64, bn = blockIdx.x*64;
    const int t = threadIdx.x;
    const int wave = t >> 6, lane = t & 63;
    const int wm = (wave >> 1)*32, wn = (wave & 1)*32;
    const int lg = lane >> 4, lr = lane & 15;
    const int nsm = bm >> 12;
    f32x4 acc[2][2];
    #pragma unroll
    for(int i = 0; i < 2; i++)
        #pragma unroll
        for(int j = 0; j < 2; j++) acc[i][j] = (f32x4){0.f,0.f,0.f,0.f};

    float gmu = 0.f, grs = 0.f;
    if(AGN){
        float a = 0.f, q = 0.f;
        for(int idx = lane; idx < gncount; idx += 64){
            a += gnpart[(nsm*gncount + idx)*2];
            q += gnpart[(nsm*gncount + idx)*2 + 1];
        }
        #pragma unroll
        for(int off = 32; off > 0; off >>= 1){
            a += __shfl_xor(a, off, 64); q += __shfl_xor(q, off, 64);
        }
        const float inv = 1.f/(float)(HH*WW*CC);
        gmu = a*inv;
        grs = rsqrtf(fmaxf(q*inv - gmu*gmu, 0.f) + 1e-5f);
    }

    for(int k0 = 0; k0 < K; k0 += 128){
        uint4 ra[4], rb[4];
        float4 fa[4][2];
        #pragma unroll
        for(int r = 0; r < 4; r++){
            int e = r*256 + t;
            int row = e >> 4, ch = e & 15;
            if(AGN){
                const float* ap = (const float*)Av + (size_t)(bm+row)*K + k0 + ch*8;
                fa[r][0] = *(const float4*)ap;
                fa[r][1] = *(const float4*)(ap + 4);
            } else {
                ra[r] = *(const uint4*)((const u16*)Av + (size_t)(bm+row)*K + k0 + ch*8);
            }
            rb[r] = (bn+row < N) ? *(const uint4*)(W + (size_t)(bn+row)*K + k0 + ch*8)
                                 : (uint4){0,0,0,0};
        }
        #pragma unroll
        for(int r = 0; r < 4; r++){
            int e = r*256 + t;
            int row = e >> 4, ch = e & 15;
            if(AGN){
                union { uint4 u; u16 h[8]; } g8, b8, o8;
                g8.u = *(const uint4*)(gnw + k0 + ch*8);
                b8.u = *(const uint4*)(gnb + k0 + ch*8);
                const float* fv = (const float*)&fa[r][0];
                #pragma unroll
                for(int z = 0; z < 8; z++)
                    o8.h[z] = f2u((fv[z]-gmu)*grs*u2f(g8.h[z]) + u2f(b8.h[z]));
                *(uint4*)&As[row*LDP + ch*8] = o8.u;
            } else {
                *(uint4*)&As[row*LDP + ch*8] = ra[r];
            }
            *(uint4*)&Bs[row*LDP + ch*8] = rb[r];
        }
        __syncthreads();
        #pragma unroll
        for(int kc = 0; kc < 4; kc++){
            bf16x8 af0 = *(const bf16x8*)&As[(wm + lr)*LDP      + kc*32 + lg*8];
            bf16x8 af1 = *(const bf16x8*)&As[(wm + 16 + lr)*LDP + kc*32 + lg*8];
            bf16x8 bf0 = *(const bf16x8*)&Bs[(wn + lr)*LDP      + kc*32 + lg*8];
            bf16x8 bf1 = *(const bf16x8*)&Bs[(wn + 16 + lr)*LDP + kc*32 + lg*8];
            acc[0][0] = __builtin_amdgcn_mfma_f32_16x16x32_bf16(af0, bf0, acc[0][0], 0, 0, 0);
            acc[0][1] = __builtin_amdgcn_mfma_f32_16x16x32_bf16(af0, bf1, acc[0][1], 0, 0, 0);
            acc[1][0] = __builtin_amdgcn_mfma_f32_16x16x32_bf16(af1, bf0, acc[1][0], 0, 0, 0);
            acc[1][1] = __builtin_amdgcn_mfma_f32_16x16x32_bf16(af1, bf1, acc[1][1], 0, 0, 0);
        }
        if(k0 + 128 < K) __syncthreads();
    }

    float ssum = 0.f, sq = 0.f;
    #pragma unroll
    for(int i = 0; i < 2; i++){
        #pragma unroll
        for(int j = 0; j < 2; j++){
            int col = bn + wn + j*16 + lr;
            if(col >= N) continue;
            #pragma unroll
            for(int reg = 0; reg < 4; reg++){
                int row = bm + wm + i*16 + lg*4 + reg;
                float v = acc[i][j][reg] + u2f(bias[col]);
                if(EPI == EPI_RES)  v += R[(size_t)row*N + col];
                if(EPI == EPI_GELU) v = 0.5f*v*(1.f + erff(v*0.70710678118f));
                if(OUTM == OUT_F32 || OUTM == OUT_BOTH) Cf[(size_t)row*N + col] = v;
                if(OUTM == OUT_BF16 || OUTM == OUT_BOTH) Cb[(size_t)row*N + col] = f2u(v);
                if(EXTRA == EX_STATS){ ssum += v; sq += v*v; }
            }
        }
    }
    if(EXTRA == EX_STATS){
        #pragma unroll
        for(int off = 32; off > 0; off >>= 1){
            ssum += __shfl_xor(ssum, off, 64); sq += __shfl_xor(sq, off, 64);
        }
        if(lane == 0){ wred[wave][0] = ssum; wred[wave][1] = sq; }
        __syncthreads();
        if(t == 0){
            int bidx = blockIdx.y*gridDim.x + blockIdx.x;
            gnpart[bidx*2]   = wred[0][0]+wred[1][0]+wred[2][0]+wred[3][0];
            gnpart[bidx*2+1] = wred[0][1]+wred[1][1]+wred[2][1]+wred[3][1];
        }
    }
}

// ---------------- proj + residual + LayerNorm fused (M-tile 32; R8-validated) ----------------
__global__ __launch_bounds__(256) void proj_ln_k(
    const u16* __restrict__ A, const u16* __restrict__ W, const u16* __restrict__ bias,
    const float* __restrict__ R, const u16* __restrict__ lng, const u16* __restrict__ lnb,
    float* __restrict__ abuf, u16* __restrict__ lnout)
{
    __shared__ __align__(16) u16 As[32*LDP];
    __shared__ __align__(16) u16 Bs[128*LDP];
    __shared__ float redS[32][2], redQ[32][2], muS[32], rsS[32];
    const int bm = blockIdx.x*32;
    const int t = threadIdx.x;
    const int wave = t >> 6, lane = t & 63;
    const int wm = (wave >> 1)*16, wn = (wave & 1)*64;
    const int lg = lane >> 4, lr = lane & 15;

    {
        uint4 ra[2], rb[8];
        #pragma unroll
        for(int r = 0; r < 2; r++){
            int e = r*256 + t; int row = e >> 4, ch = e & 15;
            ra[r] = *(const uint4*)(A + (size_t)(bm+row)*CC + ch*8);
        }
        #pragma unroll
        for(int r = 0; r < 8; r++){
            int e = r*256 + t; int row = e >> 4, ch = e & 15;
            rb[r] = *(const uint4*)(W + (size_t)row*CC + ch*8);
        }
        #pragma unroll
        for(int r = 0; r < 2; r++){
            int e = r*256 + t; int row = e >> 4, ch = e & 15;
            *(uint4*)&As[row*LDP + ch*8] = ra[r];
        }
        #pragma unroll
        for(int r = 0; r < 8; r++){
            int e = r*256 + t; int row = e >> 4, ch = e & 15;
            *(uint4*)&Bs[row*LDP + ch*8] = rb[r];
        }
    }
    __syncthreads();

    f32x4 acc[4];
    #pragma unroll
    for(int j = 0; j < 4; j++) acc[j] = (f32x4){0.f,0.f,0.f,0.f};
    #pragma unroll
    for(int kc = 0; kc < 4; kc++){
        bf16x8 af = *(const bf16x8*)&As[(wm + lr)*LDP + kc*32 + lg*8];
        #pragma unroll
        for(int j = 0; j < 4; j++){
            bf16x8 bf = *(const bf16x8*)&Bs[(wn + j*16 + lr)*LDP + kc*32 + lg*8];
            acc[j] = __builtin_amdgcn_mfma_f32_16x16x32_bf16(af, bf, acc[j], 0, 0, 0);
        }
    }
    #pragma unroll
    for(int reg = 0; reg < 4; reg++){
        int rl = wm + lg*4 + reg;
        float rs_ = 0.f, rq_ = 0.f;
        #pragma unroll
        for(int j = 0; j < 4; j++){
            int col = wn + j*16 + lr;
            float v = acc[j][reg] + u2f(bias[col]) + R[(size_t)(bm+rl)*CC + col];
            acc[j][reg] = v;
            abuf[(size_t)(bm+rl)*CC + col] = v;
            rs_ += v; rq_ += v*v;
        }
        rs_ += __shfl_xor(rs_, 1, 64); rq_ += __shfl_xor(rq_, 1, 64);
        rs_ += __shfl_xor(rs_, 2, 64); rq_ += __shfl_xor(rq_, 2, 64);
        rs_ += __shfl_xor(rs_, 4, 64); rq_ += __shfl_xor(rq_, 4, 64);
        rs_ += __shfl_xor(rs_, 8, 64); rq_ += __shfl_xor(rq_, 8, 64);
        if(lr == 0){ redS[rl][wn>>6] = rs_; redQ[rl][wn>>6] = rq_; }
    }
    __syncthreads();
    if(t < 32){
        float mu = (redS[t][0] + redS[t][1])*(1.f/CC);
        float var = fmaxf((redQ[t][0] + redQ[t][1])*(1.f/CC) - mu*mu, 0.f);
        muS[t] = mu; rsS[t] = rsqrtf(var + 1e-5f);
    }
    __syncthreads();
    #pragma unroll
    for(int reg = 0; reg < 4; reg++){
        int rl = wm + lg*4 + reg;
        float mu = muS[rl], rstd = rsS[rl];
        #pragma unroll
        for(int j = 0; j < 4; j++){
            int col = wn + j*16 + lr;
            float v = (acc[j][reg] - mu)*rstd*u2f(lng[col]) + u2f(lnb[col]);
            lnout[(size_t)(bm+rl)*CC + col] = f2u(v);
        }
    }
}

// ---------------- fused conv3x3 + c1(ReLU) + c2 + pool (M-tile 16, 512 blocks) ----------------
__global__ __launch_bounds__(256) void mct_k(
    const u16* __restrict__ in, const u16* __restrict__ Wt, const u16* __restrict__ bias,
    const u16* __restrict__ c1w, const u16* __restrict__ c1b,
    const u16* __restrict__ c2w, const u16* __restrict__ c2b,
    float* __restrict__ ybuf, float* __restrict__ poolacc)
{
    __shared__ __align__(16) u16 As[16*LDP];
    __shared__ __align__(16) u16 Bs[128*LDP];
    u16* Bs1 = Bs;                       // c1w [32][LDP] (aliases dead conv-B)
    u16* Bs2 = Bs + 32*LDP;              // c2w [128][40]
    u16* Hs  = Bs + 32*LDP + 128*40;     // h   [16][40]
    const int bm = blockIdx.x*16;
    const int t = threadIdx.x;
    const int wave = t >> 6, lane = t & 63;
    const int wn = wave*32;              // each wave: 16 rows x 32 cols
    const int lg = lane >> 4, lr = lane & 15;
    const int nsm = bm >> 12;

    // preload tail weights into registers (live across conv loop)
    uint4 rb1[2], rb2[2];
    #pragma unroll
    for(int r = 0; r < 2; r++){
        int e = r*256 + t; int row = e >> 4, ch = e & 15;
        rb1[r] = *(const uint4*)(c1w + (size_t)row*CC + ch*8);
    }
    #pragma unroll
    for(int r = 0; r < 2; r++){
        int e = r*256 + t; int row = e >> 2, ch = e & 3;
        rb2[r] = *(const uint4*)(c2w + (size_t)row*C4 + ch*8);
    }

    f32x4 acc[2];
    acc[0] = (f32x4){0.f,0.f,0.f,0.f}; acc[1] = (f32x4){0.f,0.f,0.f,0.f};

    for(int tap = 0; tap < 9; tap++){
        int dy = tap/3 - 1, dx = tap%3 - 1;
        uint4 ra, rb[8];
        {
            int row = t >> 4, ch = t & 15;
            int p = bm + row;
            int n = p >> 12, ii = (p & 4095) >> 6, jj = p & 63;
            int y = ii + dy, x = jj + dx;
            ra = (uint4){0,0,0,0};
            if(y >= 0 && y < HH && x >= 0 && x < WW)
                ra = *(const uint4*)(in + (size_t)(((n*HH + y)*WW + x))*CC + ch*8);
        }
        #pragma unroll
        for(int r = 0; r < 8; r++){
            int e = r*256 + t; int row = e >> 4, ch = e & 15;
            rb[r] = *(const uint4*)(Wt + (size_t)row*(9*CC) + tap*128 + ch*8);
        }
        {
            int row = t >> 4, ch = t & 15;
            *(uint4*)&As[row*LDP + ch*8] = ra;
        }
        #pragma unroll
        for(int r = 0; r < 8; r++){
            int e = r*256 + t; int row = e >> 4, ch = e & 15;
            *(uint4*)&Bs[row*LDP + ch*8] = rb[r];
        }
        __syncthreads();
        #pragma unroll
        for(int kc = 0; kc < 4; kc++){
            bf16x8 af = *(const bf16x8*)&As[lr*LDP + kc*32 + lg*8];
            #pragma unroll
            for(int j = 0; j < 2; j++){
                bf16x8 bf = *(const bf16x8*)&Bs[(wn + j*16 + lr)*LDP + kc*32 + lg*8];
                acc[j] = __builtin_amdgcn_mfma_f32_16x16x32_bf16(af, bf, acc[j], 0, 0, 0);
            }
        }
        __syncthreads();
    }

    // conv epilogue: +bias -> conv-out bf16 into As; stage tail weights into dead Bs
    #pragma unroll
    for(int j = 0; j < 2; j++){
        int col = wn + j*16 + lr;
        #pragma unroll
        for(int reg = 0; reg < 4; reg++){
            int rl = lg*4 + reg;
            As[rl*LDP + col] = f2u(acc[j][reg] + u2f(bias[col]));
        }
    }
    #pragma unroll
    for(int r = 0; r < 2; r++){
        int e = r*256 + t; int row = e >> 4, ch = e & 15;
        *(uint4*)&Bs1[row*LDP + ch*8] = rb1[r];
    }
    #pragma unroll
    for(int r = 0; r < 2; r++){
        int e = r*256 + t; int row = e >> 2, ch = e & 3;
        *(uint4*)&Bs2[row*40 + ch*8] = rb2[r];
    }
    __syncthreads();

    // GEMM1: h[16,32] = relu(convout @ c1w^T + c1b)  (wave pairs duplicate, benign)
    {
        const int wn1 = (wave & 1)*16;
        f32x4 a1 = (f32x4){0.f,0.f,0.f,0.f};
        #pragma unroll
        for(int kc = 0; kc < 4; kc++){
            bf16x8 af = *(const bf16x8*)&As[lr*LDP + kc*32 + lg*8];
            bf16x8 bf = *(const bf16x8*)&Bs1[(wn1 + lr)*LDP + kc*32 + lg*8];
            a1 = __builtin_amdgcn_mfma_f32_16x16x32_bf16(af, bf, a1, 0, 0, 0);
        }
        #pragma unroll
        for(int reg = 0; reg < 4; reg++){
            int rl = lg*4 + reg;
            int col = wn1 + lr;
            Hs[rl*40 + col] = f2u(fmaxf(a1[reg] + u2f(c1b[col]), 0.f));
        }
    }
    __syncthreads();

    // GEMM2: y[16,128] = h @ c2w^T + c2b; f32 out + pool atomics
    {
        f32x4 a2[2];
        a2[0] = (f32x4){0.f,0.f,0.f,0.f}; a2[1] = (f32x4){0.f,0.f,0.f,0.f};
        bf16x8 af = *(const bf16x8*)&Hs[lr*40 + lg*8];
        #pragma unroll
        for(int j = 0; j < 2; j++){
            bf16x8 bf = *(const bf16x8*)&Bs2[(wn + j*16 + lr)*40 + lg*8];
            a2[j] = __builtin_amdgcn_mfma_f32_16x16x32_bf16(af, bf, a2[j], 0, 0, 0);
        }
        float cs[2] = {0.f, 0.f};
        #pragma unroll
        for(int j = 0; j < 2; j++){
            int col = wn + j*16 + lr;
            #pragma unroll
            for(int reg = 0; reg < 4; reg++){
                int row = bm + lg*4 + reg;
                float v = a2[j][reg] + u2f(c2b[col]);
                ybuf[(size_t)row*CC + col] = v;
                cs[j] += v;
            }
        }
        #pragma unroll
        for(int j = 0; j < 2; j++){
            cs[j] += __shfl_xor(cs[j], 16, 64);
            cs[j] += __shfl_xor(cs[j], 32, 64);
        }
        if(lg == 0){
            #pragma unroll
            for(int j = 0; j < 2; j++)
                atomicAdd(&poolacc[nsm*CC + wn + j*16 + lr], cs[j]);
        }
    }
}

// ---------------- MFMA tiled neighborhood attention; P aliased over K-LDS ----------------
#define KVP 72
#define PSP 168

__global__ __launch_bounds__(128) void att_tile_k(
    const u16* __restrict__ qkv, const u16* __restrict__ rpb, u16* __restrict__ out)
{
    __shared__ __align__(16) u16 KV[2][RNB][KVP];
    __shared__ __align__(16) u16 Qs[16][64];
    __shared__ float rpbs[2][169];
    u16* PsB = &KV[0][0][0];
    const int blk = blockIdx.x;
    const int rb = blk >> 1, eg = blk & 1;
    const int p0 = rb*16;
    const int jb = p0 & 63, i = (p0 >> 6) & 63, n = p0 >> 12;
    const int i0 = min(max(i-3, 0), HH-KSZ);
    const int rc0 = min(max(jb-3, 0), WW-KSZ);
    const int t = threadIdx.x;

    for(int idx = t; idx < 2*169; idx += 128)
        rpbs[idx/169][idx%169] = u2f(rpb[(eg*2 + idx/169)*169 + idx%169]);
    {
        int pix = t >> 3, ch = t & 7;
        *(uint4*)&Qs[pix][ch*8] = *(const uint4*)(qkv + (size_t)(p0+pix)*(3*CC) + eg*64 + ch*8);
    }
    for(int idx = t; idx < RNB*16; idx += 128){
        int nb = idx >> 4, part = idx & 15;
        int kv = part >> 3, ch = part & 7;
        uint4 v = (uint4){0,0,0,0};
        if(nb < NBV){
            int ky = nb/RW, kcol = nb - ky*RW;
            int sy = i0 + ky, sx = min(rc0 + kcol, WW-1);
            v = *(const uint4*)(qkv + (size_t)((n*HH + sy)*WW + sx)*(3*CC) + CC + kv*CC + eg*64 + ch*8);
        }
        *(uint4*)&KV[kv][nb][ch*8] = v;
    }
    __syncthreads();

    const int el = t >> 6;
    const int lane = t & 63, lg = lane >> 4, lr = lane & 15;

    bf16x8 aq = *(const bf16x8*)&Qs[lr][el*32 + lg*8];
    f32x4 sc[10];
    #pragma unroll
    for(int c = 0; c < 10; c++){
        bf16x8 bk = *(const bf16x8*)&KV[0][c*16+lr][el*32 + lg*8];
        sc[c] = __builtin_amdgcn_mfma_f32_16x16x32_bf16(aq, bk, (f32x4){0.f,0.f,0.f,0.f}, 0, 0, 0);
    }
    __syncthreads();
    #pragma unroll
    for(int reg = 0; reg < 4; reg++){
        int pix = lg*4 + reg;
        int j = jb + pix;
        int base = min(max(j-3, 0), WW-KSZ) - rc0;
        float mx = -1e30f;
        #pragma unroll
        for(int c = 0; c < 10; c++){
            int nb = c*16 + lr;
            int ky = nb/RW, kcol = nb - ky*RW;
            float v = -1e30f;
            if(nb < NBV && kcol >= base && kcol <= base+6){
                int ri = i0 + ky - i + (KSZ-1);
                int rj = rc0 + kcol - j + (KSZ-1);
                v = sc[c][reg]*0.17677669529663689f + rpbs[el][ri*13 + rj];
            }
            sc[c][reg] = v;
            mx = fmaxf(mx, v);
        }
        mx = fmaxf(mx, __shfl_xor(mx, 1, 64));
        mx = fmaxf(mx, __shfl_xor(mx, 2, 64));
        mx = fmaxf(mx, __shfl_xor(mx, 4, 64));
        mx = fmaxf(mx, __shfl_xor(mx, 8, 64));
        float sum = 0.f;
        #pragma unroll
        for(int c = 0; c < 10; c++){
            float p = __expf(sc[c][reg] - mx);
            sc[c][reg] = p; sum += p;
        }
        sum += __shfl_xor(sum, 1, 64);
        sum += __shfl_xor(sum, 2, 64);
        sum += __shfl_xor(sum, 4, 64);
        sum += __shfl_xor(sum, 8, 64);
        float rs = 1.f/sum;
        #pragma unroll
        for(int c = 0; c < 10; c++)
            PsB[(el*16 + pix)*PSP + c*16 + lr] = f2u(sc[c][reg]*rs);
    }
    __syncthreads();
    f32x4 o0 = (f32x4){0.f,0.f,0.f,0.f}, o1 = (f32x4){0.f,0.f,0.f,0.f};
    #pragma unroll
    for(int ks = 0; ks < 5; ks++){
        bf16x8 ap = *(const bf16x8*)&PsB[(el*16 + lr)*PSP + ks*32 + lg*8];
        bf16x8 b0, b1;
        #pragma unroll
        for(int jj = 0; jj < 8; jj++){
            int nb = ks*32 + lg*8 + jj;
            b0[jj] = (short)KV[1][nb][el*32 + lr];
            b1[jj] = (short)KV[1][nb][el*32 + 16 + lr];
        }
        o0 = __builtin_amdgcn_mfma_f32_16x16x32_bf16(ap, b0, o0, 0, 0, 0);
        o1 = __builtin_amdgcn_mfma_f32_16x16x32_bf16(ap, b1, o1, 0, 0, 0);
    }
    int e = eg*2 + el;
    #pragma unroll
    for(int reg = 0; reg < 4; reg++){
        int pix = lg*4 + reg;
        out[(size_t)(p0+pix)*CC + e*32 + lr]      = f2u(o0[reg]);
        out[(size_t)(p0+pix)*CC + e*32 + 16 + lr] = f2u(o1[reg]);
    }
}

// ---------------- final: inline CA MLP + scale + residual + NCHW store ----------------
__global__ __launch_bounds__(256) void final_ca_k(
    const float* __restrict__ y, const float* __restrict__ poolacc,
    const u16* __restrict__ w1, const u16* __restrict__ b1,
    const u16* __restrict__ w2, const u16* __restrict__ b2,
    const void* __restrict__ xraw, void* __restrict__ outv,
    const int* __restrict__ flag)
{
    __shared__ float t1s[CRED];
    __shared__ float sres;
    int id0 = blockIdx.x*256;
    int c = (id0 >> 12) & (CC-1);
    int n = id0 >> 19;
    int t = threadIdx.x;
    if(t < CRED){
        float a = u2f(b1[t]);
        const float pscale = 1.f/(float)(HH*WW);
        for(int cc = 0; cc < CC; cc++)
            a += poolacc[n*CC + cc]*pscale*u2f(w1[t*CC + cc]);
        t1s[t] = fmaxf(a, 0.f);
    }
    __syncthreads();
    if(t == 0){
        float a = u2f(b2[c]);
        #pragma unroll
        for(int r = 0; r < CRED; r++) a += t1s[r]*u2f(w2[c*CRED + r]);
        sres = 1.f/(1.f + __expf(-a));
    }
    __syncthreads();
    float s = sres;
    int id = id0 + t;
    int j = id & 63; int i = (id >> 6) & 63;
    float xr = (*flag) ? ((const float*)xraw)[id] : u2f(((const u16*)xraw)[id]);
    float v = y[(size_t)((n*HH + i)*WW + j)*CC + c]*s + xr;
    if(*flag) ((float*)outv)[id] = v;
    else      ((u16*)outv)[id] = f2u(v);
}

// ---------------- host ----------------
extern "C" void kernel_launch(void* const* d_in, const int* in_sizes, int n_in,
                              void* d_out, int out_size, void* d_ws, size_t ws_size,
                              hipStream_t stream){
    float* wsf    = (float*)d_ws;
    int*   flagp  = (int*)d_ws;
    float* gnpart = wsf + 8;
    float* poolacc= wsf + 1040;

    u16* Wb = (u16*)(wsf + 2048);
    static const int wsizes[23] = {256,256,98304,768,32768,256,1352,256,256,131072,1024,
                                   131072,256,147456,128,4096,32,4096,128,896,7,896,128};
    int woff[24]; woff[0] = 0;
    for(int i = 0; i < 23; i++) woff[i+1] = woff[i] + wsizes[i];
    const int WTOT = woff[23];
    u16* Wt = Wb + 555760;

    float* AB    = wsf + 360448;
    float* cur   = AB;                                   // f32 residual stream
    u16*  cur16  = (u16*)(AB + 1048576);
    u16*  xg16   = (u16*)(AB + 1572864);                 // attn-out / ln-out
    u16*  qkv16  = (u16*)(AB + 2097152);
    float* abuf  = AB + 2097152;                         // aliases qkv16 (dead after att)
    u16*  hbuf16 = (u16*)(AB + 3670016);
    float* ybuf  = AB + 3670016;                         // aliases hbuf16 (dead after fc2)

    detect_k<<<1, 256, 0, stream>>>((const u16*)d_in[0], flagp, poolacc);

    PtrTab tab;
    for(int i = 0; i < 23; i++){ tab.p[i] = d_in[i+1]; tab.off[i] = woff[i]; }
    tab.off[23] = woff[23];
    setup_k<<<NCVT + NRPK + NNCH, 256, 0, stream>>>(
        tab, Wb, Wt, d_in[14], d_in[0], cur, gnpart, flagp, WTOT);

    const u16 *gng = Wb+woff[0], *gnb = Wb+woff[1], *qkvw = Wb+woff[2], *qkvb = Wb+woff[3],
              *projw = Wb+woff[4], *projb = Wb+woff[5], *rpbw = Wb+woff[6], *lng = Wb+woff[7],
              *lnb = Wb+woff[8], *f1w = Wb+woff[9], *f1b = Wb+woff[10], *f2w = Wb+woff[11],
              *f2b = Wb+woff[12], *bcb = Wb+woff[14], *c1w = Wb+woff[15],
              *c1b = Wb+woff[16], *c2w = Wb+woff[17], *c2b = Wb+woff[18], *ca1w = Wb+woff[19],
              *ca1b = Wb+woff[20], *ca2w = Wb+woff[21], *ca2b = Wb+woff[22];

    for(int l = 0; l < 2; l++){
        int gncount = (l == 0) ? 256 : 128;

        g64_k<EPI_NONE,OUT_BF16,1,EX_NONE><<<dim3(6, PIX/64), 256, 0, stream>>>(
            cur, qkvw + (size_t)l*3*CC*CC, qkvb + l*3*CC, nullptr, nullptr, qkv16,
            gng + l*CC, gnb + l*CC, gnpart, gncount, PIX, 3*CC, CC);

        att_tile_k<<<PIX/16*2, 128, 0, stream>>>(qkv16, rpbw + l*NHD*169, xg16);

        proj_ln_k<<<PIX/32, 256, 0, stream>>>(
            xg16, projw + (size_t)l*CC*CC, projb + l*CC, cur, lng + l*CC, lnb + l*CC,
            abuf, xg16);

        g64_k<EPI_GELU,OUT_BF16,0,EX_NONE><<<dim3(8, PIX/64), 256, 0, stream>>>(
            xg16, f1w + (size_t)l*HID*CC, f1b + l*HID, nullptr, nullptr, hbuf16,
            nullptr, nullptr, nullptr, 0, PIX, HID, CC);

        g64_k<EPI_RES,OUT_BOTH,0,EX_STATS><<<dim3(2, PIX/64), 256, 0, stream>>>(
            hbuf16, f2w + (size_t)l*CC*HID, f2b + l*CC, abuf, cur, cur16,
            nullptr, nullptr, gnpart, 0, PIX, CC, HID);
    }

    mct_k<<<PIX/16, 256, 0, stream>>>(cur16, Wt, bcb, c1w, c1b, c2w, c2b, ybuf, poolacc);

    final_ca_k<<<(NN*CC*HH*WW)/256, 256, 0, stream>>>(
        ybuf, poolacc, ca1w, ca1b, ca2w, ca2b, d_in[0], d_out, flagp);
}